// Round 4
// baseline (1302.995 us; speedup 1.0000x reference)
//
#include <hip/hip_runtime.h>
#include <hip/hip_bf16.h>

#define PM    10000
#define NP_N  50
#define EP_N  200
#define EM_N  160000
#define OUT_C 16
#define EPSV  1e-5f

typedef __attribute__((ext_vector_type(8))) short short8;
typedef __attribute__((ext_vector_type(4))) float f32x4;

// workspace layout (float offsets)
#define OFF_DEGO   0          // [10016]
#define OFF_DEGI   10016
#define OFF_OFFS   20032      // int [10001]
#define OFF_CUR    30048      // int [10000]
#define OFF_CSRC   40064      // int [160000]
#define OFF_CSRW   200064     // f32 [160000]
#define OFF_STATS  360064     // sums1[256] sq1[256] sums2[256] sq2[256] ro[512]
#define OFF_W1S    361600     // 16384 bf16 = 8192 f-slots
#define OFF_W2S    369792
#define OFF_RBUF   377984     // f32 [PM][384]  (HROW bf16 [PM][256] overlays later)
#define OFF_EMB    4217984    // f32 [PM][128]
#define OFF_X1T    5497984    // f32 [256][PM]  (X2T overlays later)

__device__ __forceinline__ ushort f2bf(float f){
    __hip_bfloat16 h = __float2bfloat16(f);
    return *reinterpret_cast<ushort*>(&h);
}
__device__ __forceinline__ uint pack2(float a, float b){
    return (uint)f2bf(a) | ((uint)f2bf(b) << 16);
}

// ---------------------------------------------------------------------------
// prep: swizzle W1 [64][256] and W2 [256][64] into bf16 MFMA B-fragment order
// B[k][n], k = ki*32 + (l>>4)*8 + j, n = ct*16 + (l&15) -> frag[(grp*64+l)*8+j]
// W1: grp = ct*2 + ki (ct 0..15, ki 0..1); W2: grp = ct*8 + ki (ct 0..3, ki 0..7)
// ---------------------------------------------------------------------------
__global__ __launch_bounds__(256) void prep_kernel(
    const float* __restrict__ W1, const float* __restrict__ W2,
    ushort* __restrict__ W1s, ushort* __restrict__ W2s)
{
    int gid = blockIdx.x * 256 + threadIdx.x;
    if (gid < 16384){
        int j = gid & 7, l = (gid >> 3) & 63, ki = (gid >> 9) & 1, ct = gid >> 10;
        int k = ki * 32 + ((l >> 4) << 3) + j;
        int n = ct * 16 + (l & 15);
        W1s[gid] = f2bf(W1[k * 256 + n]);
    } else {
        int g = gid - 16384;
        int j = g & 7, l = (g >> 3) & 63, ki = (g >> 9) & 7, ct = g >> 12;
        int k = ki * 32 + ((l >> 4) << 3) + j;
        int n = ct * 16 + (l & 15);
        W2s[g] = f2bf(W2[k * 64 + n]);
    }
}

// ---------------------------------------------------------------------------
// Patch embedder: all-MFMA, one block (4 waves) per patch. Writes r[384].
// ---------------------------------------------------------------------------
__global__ __launch_bounds__(256, 5) void patch_kernel(
    const float* __restrict__ feats, const int* __restrict__ esrc,
    const int* __restrict__ edst, const float* __restrict__ eew,
    const ushort* __restrict__ W1s, const float* __restrict__ g1,
    const float* __restrict__ b1, const ushort* __restrict__ W2s,
    const float* __restrict__ g2, const float* __restrict__ b2,
    float* __restrict__ rbuf)
{
    __shared__ __align__(16) char smem[29184];
    float* s_A  = (float*)smem;              // [64][68] f32 (dies after frag extract)
    char*  s_h1 = smem;                      // bf16 half-h1, 64 rows x 272B, swizzled
    char*  s_G1 = smem + 17408;              // bf16 G1, 64 rows x 144B, swizzled
    float* s_deg = (float*)(smem + 26624);   // 128
    float* s_rs  = (float*)(smem + 27136);   // 128
    float* s_r   = (float*)(smem + 27648);   // 384

    const int tid  = threadIdx.x;
    const int p    = blockIdx.x;
    const int lane = tid & 63;
    const int wv   = tid >> 6;
    const int lnlo = lane & 15;
    const int lghi = lane >> 4;

    // ---- feat direct-to-register loads (B-frags for conv1), issued early
    float fl[2][8];
    {
        const float* fbase = feats + (size_t)p * 3200 + wv * 16 + lnlo;
        #pragma unroll
        for (int ki = 0; ki < 2; ++ki)
            #pragma unroll
            for (int j = 0; j < 8; ++j){
                int s = ki * 32 + lghi * 8 + j;
                int sc = (s < NP_N) ? s : (NP_N - 1);
                fl[ki][j] = fbase[sc * 64];
            }
    }
    // ---- edge loads
    int es = 0, ed = 0; float ewt = 0.f;
    if (tid < EP_N){
        es  = esrc[p * EP_N + tid];
        ed  = edst[p * EP_N + tid];
        ewt = eew[p * EP_N + tid];
    }
    // ---- zero A + deg
    for (int i = tid; i < 1088; i += 256)
        *(float4*)&s_A[i * 4] = make_float4(0.f, 0.f, 0.f, 0.f);
    if (tid < 128) s_deg[tid] = 0.f;
    __syncthreads();
    if (tid < EP_N){
        atomicAdd(&s_deg[es], 1.f);
        atomicAdd(&s_deg[64 + ed], 1.f);
    }
    // r0 partial while atomics fly
    float r0s = 0.f;
    #pragma unroll
    for (int ki = 0; ki < 2; ++ki)
        #pragma unroll
        for (int j = 0; j < 8; ++j)
            r0s += (ki * 32 + lghi * 8 + j < NP_N) ? fl[ki][j] : 0.f;
    r0s += __shfl_xor(r0s, 16); r0s += __shfl_xor(r0s, 32);
    __syncthreads();
    if (tid < 128) s_rs[tid] = rsqrtf(fmaxf(s_deg[tid], 1.f));
    if (lghi == 0) s_r[wv * 16 + lnlo] = r0s * 0.02f;
    // convert feat to bf16 frags
    short8 fbf[2];
    #pragma unroll
    for (int ki = 0; ki < 2; ++ki)
        #pragma unroll
        for (int j = 0; j < 8; ++j)
            fbf[ki][j] = (short)f2bf(fl[ki][j]);
    __syncthreads();
    // ---- normalized adjacency: 200 atomics with rs folded
    if (tid < EP_N)
        atomicAdd(&s_A[ed * 68 + es], ewt * s_rs[es] * s_rs[64 + ed]);
    __syncthreads();
    // ---- extract A-frags (bf16), reused by conv1 & conv2
    short8 afr[4][2];
    #pragma unroll
    for (int rt = 0; rt < 4; ++rt)
        #pragma unroll
        for (int ki = 0; ki < 2; ++ki){
            int row = rt * 16 + lnlo, k0 = ki * 32 + lghi * 8;
            float4 f0 = *(const float4*)&s_A[row * 68 + k0];
            float4 f1 = *(const float4*)&s_A[row * 68 + k0 + 4];
            short8 sv;
            sv[0] = (short)f2bf(f0.x); sv[1] = (short)f2bf(f0.y);
            sv[2] = (short)f2bf(f0.z); sv[3] = (short)f2bf(f0.w);
            sv[4] = (short)f2bf(f1.x); sv[5] = (short)f2bf(f1.y);
            sv[6] = (short)f2bf(f1.z); sv[7] = (short)f2bf(f1.w);
            afr[rt][ki] = sv;
        }
    // ---- conv1: G1 = A~ @ feat
    f32x4 cacc[4];
    #pragma unroll
    for (int rt = 0; rt < 4; ++rt) cacc[rt] = (f32x4){0.f,0.f,0.f,0.f};
    #pragma unroll
    for (int rt = 0; rt < 4; ++rt){
        cacc[rt] = __builtin_amdgcn_mfma_f32_16x16x32_bf16(afr[rt][0], fbf[0], cacc[rt], 0,0,0);
        cacc[rt] = __builtin_amdgcn_mfma_f32_16x16x32_bf16(afr[rt][1], fbf[1], cacc[rt], 0,0,0);
    }
    #pragma unroll
    for (int rt = 0; rt < 4; ++rt)
        #pragma unroll
        for (int e = 0; e < 4; ++e){
            int row = rt * 16 + lghi * 4 + e;
            int col = wv * 16 + lnlo;
            *(ushort*)(s_G1 + row * 144 + ((col * 2) ^ ((row & 8) << 2))) = f2bf(cacc[rt][e]);
        }
    __syncthreads();

    // ---- GEMM1 (+norm+lrelu+r1 -> h1 halves) and GEMM2 (Z accumulation)
    f32x4 zacc[4];
    #pragma unroll
    for (int rt = 0; rt < 4; ++rt) zacc[rt] = (f32x4){0.f,0.f,0.f,0.f};

    for (int h = 0; h < 2; ++h){
        short8 ga[4][2];
        #pragma unroll
        for (int rt = 0; rt < 4; ++rt)
            #pragma unroll
            for (int ki = 0; ki < 2; ++ki){
                int row = rt * 16 + lnlo, k0 = ki * 32 + lghi * 8;
                ga[rt][ki] = *(const short8*)(s_G1 + row * 144 + ((k0 * 2) ^ ((row & 8) << 2)));
            }
        #pragma unroll
        for (int ctl = 0; ctl < 2; ++ctl){
            int ctg = h * 8 + wv * 2 + ctl;
            short8 wb0 = *(const short8*)&W1s[((ctg * 2 + 0) * 64 + lane) * 8];
            short8 wb1 = *(const short8*)&W1s[((ctg * 2 + 1) * 64 + lane) * 8];
            f32x4 m[4];
            #pragma unroll
            for (int rt = 0; rt < 4; ++rt) m[rt] = (f32x4){0.f,0.f,0.f,0.f};
            #pragma unroll
            for (int rt = 0; rt < 4; ++rt){
                m[rt] = __builtin_amdgcn_mfma_f32_16x16x32_bf16(ga[rt][0], wb0, m[rt], 0,0,0);
                m[rt] = __builtin_amdgcn_mfma_f32_16x16x32_bf16(ga[rt][1], wb1, m[rt], 0,0,0);
            }
            float s1 = 0.f, s2 = 0.f;
            #pragma unroll
            for (int rt = 0; rt < 4; ++rt)
                #pragma unroll
                for (int e = 0; e < 4; ++e){ float x = m[rt][e]; s1 += x; s2 += x*x; }
            s1 += __shfl_xor(s1, 16); s1 += __shfl_xor(s1, 32);
            s2 += __shfl_xor(s2, 16); s2 += __shfl_xor(s2, 32);
            float mu = s1 * 0.02f;
            float var = s2 * 0.02f - mu * mu;
            float rinv = rsqrtf(var + EPSV);
            int jg = ctg * 16 + lnlo;
            float sc = g1[jg] * rinv;
            float sh = b1[jg] - mu * sc;
            float r1p = 0.f;
            int jl = (wv * 2 + ctl) * 16 + lnlo;
            #pragma unroll
            for (int rt = 0; rt < 4; ++rt)
                #pragma unroll
                for (int e = 0; e < 4; ++e){
                    int row = rt * 16 + lghi * 4 + e;
                    float y = m[rt][e] * sc + sh;
                    float hh = (y >= 0.f) ? y : 0.01f * y;
                    hh = (row < NP_N) ? hh : 0.f;
                    r1p += hh;
                    *(ushort*)(s_h1 + row * 272 + ((jl * 2) ^ ((row & 8) << 2))) = f2bf(hh);
                }
            r1p += __shfl_xor(r1p, 16); r1p += __shfl_xor(r1p, 32);
            if (lghi == 0) s_r[64 + jg] = r1p * 0.02f;
        }
        __syncthreads();
        #pragma unroll
        for (int kil = 0; kil < 4; ++kil){
            short8 wb2 = *(const short8*)&W2s[((wv * 8 + h * 4 + kil) * 64 + lane) * 8];
            #pragma unroll
            for (int rt = 0; rt < 4; ++rt){
                int row = rt * 16 + lnlo, kl = kil * 32 + lghi * 8;
                short8 a = *(const short8*)(s_h1 + row * 272 + ((kl * 2) ^ ((row & 8) << 2)));
                zacc[rt] = __builtin_amdgcn_mfma_f32_16x16x32_bf16(a, wb2, zacc[rt], 0,0,0);
            }
        }
        __syncthreads();
    }

    // ---- Z -> conv2 B-frags, fully in-register via shuffles
    uint pk[4][2];
    #pragma unroll
    for (int rt = 0; rt < 4; ++rt){
        pk[rt][0] = pack2(zacc[rt][0], zacc[rt][1]);
        pk[rt][1] = pack2(zacc[rt][2], zacc[rt][3]);
    }
    bool hi = (lghi >= 2);
    int lane_lo = (((lghi * 2 + 0) & 3) << 4) + lnlo;
    int lane_hi = (((lghi * 2 + 1) & 3) << 4) + lnlo;
    short8 zb[2];
    #pragma unroll
    for (int ki = 0; ki < 2; ++ki){
        uint sA = hi ? pk[ki*2+1][0] : pk[ki*2][0];
        uint sB = hi ? pk[ki*2+1][1] : pk[ki*2][1];
        uint w0 = (uint)__shfl((int)sA, lane_lo, 64);
        uint w1 = (uint)__shfl((int)sB, lane_lo, 64);
        uint w2 = (uint)__shfl((int)sA, lane_hi, 64);
        uint w3 = (uint)__shfl((int)sB, lane_hi, 64);
        short8 z;
        z[0] = (short)(w0 & 0xffff); z[1] = (short)(w0 >> 16);
        z[2] = (short)(w1 & 0xffff); z[3] = (short)(w1 >> 16);
        z[4] = (short)(w2 & 0xffff); z[5] = (short)(w2 >> 16);
        z[6] = (short)(w3 & 0xffff); z[7] = (short)(w3 >> 16);
        zb[ki] = z;
    }
    // ---- conv2: out = A~ @ Z
    f32x4 oacc[4];
    #pragma unroll
    for (int rt = 0; rt < 4; ++rt) oacc[rt] = (f32x4){0.f,0.f,0.f,0.f};
    #pragma unroll
    for (int rt = 0; rt < 4; ++rt){
        oacc[rt] = __builtin_amdgcn_mfma_f32_16x16x32_bf16(afr[rt][0], zb[0], oacc[rt], 0,0,0);
        oacc[rt] = __builtin_amdgcn_mfma_f32_16x16x32_bf16(afr[rt][1], zb[1], oacc[rt], 0,0,0);
    }
    // ---- norm2 + lrelu + r2 from accumulators
    {
        float s1 = 0.f, s2 = 0.f;
        #pragma unroll
        for (int rt = 0; rt < 4; ++rt)
            #pragma unroll
            for (int e = 0; e < 4; ++e){ float x = oacc[rt][e]; s1 += x; s2 += x*x; }
        s1 += __shfl_xor(s1, 16); s1 += __shfl_xor(s1, 32);
        s2 += __shfl_xor(s2, 16); s2 += __shfl_xor(s2, 32);
        float mu = s1 * 0.02f;
        float var = s2 * 0.02f - mu * mu;
        float rinv = rsqrtf(var + EPSV);
        int c2 = wv * 16 + lnlo;
        float sc = g2[c2] * rinv;
        float sh = b2[c2] - mu * sc;
        float r2p = 0.f;
        #pragma unroll
        for (int rt = 0; rt < 4; ++rt)
            #pragma unroll
            for (int e = 0; e < 4; ++e){
                int row = rt * 16 + lghi * 4 + e;
                float y = oacc[rt][e] * sc + sh;
                float hh = (y >= 0.f) ? y : 0.01f * y;
                r2p += (row < NP_N) ? hh : 0.f;
            }
        r2p += __shfl_xor(r2p, 16); r2p += __shfl_xor(r2p, 32);
        if (lghi == 0) s_r[320 + c2] = r2p * 0.02f;
    }
    __syncthreads();
    if (tid < 96)
        *(float4*)&rbuf[(size_t)p * 384 + tid * 4] = *(const float4*)&s_r[tid * 4];
}

// ---------------------------------------------------------------------------
// emb = InstanceNorm(lrelu?)... : emb_pre = R @ We, per-row norm + lrelu
// ---------------------------------------------------------------------------
__global__ __launch_bounds__(256) void emb_kernel(
    const float* __restrict__ rbuf, const float* __restrict__ We,
    float* __restrict__ emb)
{
    __shared__ float s_R[16 * 388];
    int tid = threadIdx.x;
    int rb = blockIdx.x * 16;
    for (int i = tid; i < 1536; i += 256){
        int r = i / 96, q = i - r * 96;
        *(float4*)&s_R[r * 388 + q * 4] =
            *(const float4*)&rbuf[(size_t)(rb + r) * 384 + q * 4];
    }
    __syncthreads();
    int r = tid >> 4, c0 = (tid & 15) * 8;
    float acc[8];
    #pragma unroll
    for (int j = 0; j < 8; ++j) acc[j] = 0.f;
    for (int k = 0; k < 384; ++k){
        float a = s_R[r * 388 + k];
        const float* wp = &We[k * 128 + c0];
        #pragma unroll
        for (int j = 0; j < 8; ++j) acc[j] = fmaf(a, wp[j], acc[j]);
    }
    float s1 = 0.f, s2 = 0.f;
    #pragma unroll
    for (int j = 0; j < 8; ++j){ s1 += acc[j]; s2 += acc[j] * acc[j]; }
    s1 += __shfl_xor(s1, 1); s2 += __shfl_xor(s2, 1);
    s1 += __shfl_xor(s1, 2); s2 += __shfl_xor(s2, 2);
    s1 += __shfl_xor(s1, 4); s2 += __shfl_xor(s2, 4);
    s1 += __shfl_xor(s1, 8); s2 += __shfl_xor(s2, 8);
    float mu = s1 * (1.f / 128.f);
    float var = s2 * (1.f / 128.f) - mu * mu;
    float rinv = rsqrtf(var + EPSV);
    float o[8];
    #pragma unroll
    for (int j = 0; j < 8; ++j){
        float y = (acc[j] - mu) * rinv;
        o[j] = (y >= 0.f) ? y : 0.01f * y;
    }
    float* op = &emb[(size_t)(rb + r) * 128 + c0];
    *(float4*)op = make_float4(o[0], o[1], o[2], o[3]);
    *(float4*)(op + 4) = make_float4(o[4], o[5], o[6], o[7]);
}

// ---------------------------------------------------------------------------
// Mesh CSR build
// ---------------------------------------------------------------------------
__global__ __launch_bounds__(256) void deg_kernel(
    const int* __restrict__ msrc, const int* __restrict__ mdst,
    float* __restrict__ degO, float* __restrict__ degI)
{
    int e = blockIdx.x * 256 + threadIdx.x;
    if (e < EM_N){
        atomicAdd(&degO[msrc[e]], 1.f);
        atomicAdd(&degI[mdst[e]], 1.f);
    }
}

__global__ __launch_bounds__(256) void scan_kernel(
    const float* __restrict__ degI, int* __restrict__ offs)
{
    __shared__ int s_sc[256];
    int t = threadIdx.x;
    int sum = 0;
    for (int k = 0; k < 40; ++k){ int i = t * 40 + k; if (i < PM) sum += (int)degI[i]; }
    s_sc[t] = sum;
    __syncthreads();
    for (int off = 1; off < 256; off <<= 1){
        int v = (t >= off) ? s_sc[t - off] : 0;
        __syncthreads();
        s_sc[t] += v;
        __syncthreads();
    }
    int run = s_sc[t] - sum;
    for (int k = 0; k < 40; ++k){
        int i = t * 40 + k;
        if (i < PM){ offs[i] = run; run += (int)degI[i]; }
    }
    if (t == 255) offs[PM] = s_sc[255];
}

__global__ __launch_bounds__(256) void fill_kernel(
    const int* __restrict__ msrc, const int* __restrict__ mdst,
    const float* __restrict__ mew, const float* __restrict__ degO,
    const int* __restrict__ offs, int* __restrict__ cur,
    int* __restrict__ csrc, float* __restrict__ csw)
{
    int e = blockIdx.x * 256 + threadIdx.x;
    if (e < EM_N){
        int d = mdst[e], s = msrc[e];
        int pos = atomicAdd(&cur[d], 1);
        int idx = offs[d] + pos;
        csrc[idx] = s;
        csw[idx] = mew[e] * rsqrtf(fmaxf(degO[s], 1.f));
    }
}

// ---------------------------------------------------------------------------
// fused gather + gemm, layer 1: x1T = (rsI * gather(emb)) @ Wc1, + col stats
// block = 16 mesh nodes; grid 625
// ---------------------------------------------------------------------------
__global__ __launch_bounds__(256) void ggemm1_kernel(
    const float* __restrict__ emb, const int* __restrict__ offs,
    const int* __restrict__ csrc, const float* __restrict__ csw,
    const float* __restrict__ degI, const float* __restrict__ Wc1,
    float* __restrict__ x1T, float* __restrict__ sums, float* __restrict__ sumsq)
{
    __shared__ float s_agg[16 * 132];
    int tid = threadIdx.x, lane = tid & 63, w = tid >> 6;
    for (int i = 0; i < 4; ++i){
        int li = w * 4 + i;
        int d = blockIdx.x * 16 + li;
        int e0 = offs[d], e1 = offs[d + 1];
        float a0 = 0.f, a1 = 0.f;
        int e = e0;
        for (; e + 1 < e1; e += 2){
            int sA = csrc[e], sB = csrc[e + 1];
            float wA = csw[e], wB = csw[e + 1];
            float2 vA = *(const float2*)&emb[(size_t)sA * 128 + lane * 2];
            float2 vB = *(const float2*)&emb[(size_t)sB * 128 + lane * 2];
            a0 = fmaf(vA.x, wA, a0); a1 = fmaf(vA.y, wA, a1);
            a0 = fmaf(vB.x, wB, a0); a1 = fmaf(vB.y, wB, a1);
        }
        if (e < e1){
            int sA = csrc[e]; float wA = csw[e];
            float2 vA = *(const float2*)&emb[(size_t)sA * 128 + lane * 2];
            a0 = fmaf(vA.x, wA, a0); a1 = fmaf(vA.y, wA, a1);
        }
        float rs = rsqrtf(fmaxf(degI[d], 1.f));
        s_agg[li * 132 + lane * 2]     = a0 * rs;
        s_agg[li * 132 + lane * 2 + 1] = a1 * rs;
    }
    __syncthreads();
    int r = lane & 15, cg = lane >> 4;
    int c0 = w * 64 + cg * 16;
    float acc[16];
    #pragma unroll
    for (int jj = 0; jj < 16; ++jj) acc[jj] = 0.f;
    #pragma unroll 2
    for (int k = 0; k < 128; ++k){
        float a = s_agg[r * 132 + k];
        const float* wp = &Wc1[k * 256 + c0];
        #pragma unroll
        for (int jj = 0; jj < 16; ++jj) acc[jj] = fmaf(a, wp[jj], acc[jj]);
    }
    int row = blockIdx.x * 16 + r;
    #pragma unroll
    for (int jj = 0; jj < 16; ++jj) x1T[(size_t)(c0 + jj) * PM + row] = acc[jj];
    #pragma unroll
    for (int jj = 0; jj < 16; ++jj){
        float s1 = acc[jj], s2 = acc[jj] * acc[jj];
        s1 += __shfl_xor(s1, 1); s2 += __shfl_xor(s2, 1);
        s1 += __shfl_xor(s1, 2); s2 += __shfl_xor(s2, 2);
        s1 += __shfl_xor(s1, 4); s2 += __shfl_xor(s2, 4);
        s1 += __shfl_xor(s1, 8); s2 += __shfl_xor(s2, 8);
        if (r == 0){
            atomicAdd(&sums[c0 + jj], s1);
            atomicAdd(&sumsq[c0 + jj], s2);
        }
    }
}

// layer-1 norm + lrelu + transpose to row-major bf16 + readout
__global__ __launch_bounds__(256) void norm1t_kernel(
    const float* __restrict__ x1T, const float* __restrict__ sums,
    const float* __restrict__ sumsq, const float* __restrict__ g,
    const float* __restrict__ b, float* __restrict__ ro, ushort* __restrict__ hRow)
{
    __shared__ float s_tile[64][65];
    int lane = threadIdx.x & 63, wvv = threadIdx.x >> 6;
    int cg = blockIdx.y;
    int rb = blockIdx.x * 64;
    int r = rb + lane;
    for (int cc = wvv; cc < 64; cc += 4){
        int c = cg * 64 + cc;
        float mu = sums[c] * (1.f / PM);
        float var = sumsq[c] * (1.f / PM) - mu * mu;
        float sc = g[c] * rsqrtf(var + EPSV);
        float sh = b[c] - mu * sc;
        float h = 0.f;
        if (r < PM){
            float x = x1T[(size_t)c * PM + r];
            float y = sc * x + sh;
            h = (y >= 0.f) ? y : 0.01f * y;
        }
        s_tile[cc][lane] = h;
        float t = h;
        #pragma unroll
        for (int m = 32; m; m >>= 1) t += __shfl_xor(t, m);
        if (lane == 0) atomicAdd(&ro[c], t);
    }
    __syncthreads();
    for (int i = wvv; i < 64; i += 4){
        int rr = rb + i;
        if (rr < PM) hRow[(size_t)rr * 256 + cg * 64 + lane] = f2bf(s_tile[i][lane]);
    }
}

// ---------------------------------------------------------------------------
// fused gather + gemm, layer 2: x2T = (rsI * gather(hRow)) @ Wc2, + col stats
// ---------------------------------------------------------------------------
__global__ __launch_bounds__(256) void ggemm2_kernel(
    const ushort* __restrict__ hRow, const int* __restrict__ offs,
    const int* __restrict__ csrc, const float* __restrict__ csw,
    const float* __restrict__ degI, const float* __restrict__ Wc2,
    float* __restrict__ x2T, float* __restrict__ sums, float* __restrict__ sumsq)
{
    __shared__ float s_agg[16 * 260];
    int tid = threadIdx.x, lane = tid & 63, w = tid >> 6;
    for (int i = 0; i < 4; ++i){
        int li = w * 4 + i;
        int d = blockIdx.x * 16 + li;
        int e0 = offs[d], e1 = offs[d + 1];
        float a0 = 0.f, a1 = 0.f, a2 = 0.f, a3 = 0.f;
        for (int e = e0; e < e1; ++e){
            int s = csrc[e]; float wt = csw[e];
            uint2 qv = *(const uint2*)&hRow[(size_t)s * 256 + lane * 4];
            a0 = fmaf(__uint_as_float(qv.x << 16), wt, a0);
            a1 = fmaf(__uint_as_float(qv.x & 0xffff0000u), wt, a1);
            a2 = fmaf(__uint_as_float(qv.y << 16), wt, a2);
            a3 = fmaf(__uint_as_float(qv.y & 0xffff0000u), wt, a3);
        }
        float rs = rsqrtf(fmaxf(degI[d], 1.f));
        *(float4*)&s_agg[li * 260 + lane * 4] =
            make_float4(a0 * rs, a1 * rs, a2 * rs, a3 * rs);
    }
    __syncthreads();
    int r = lane & 15, cg = lane >> 4;
    int c0 = w * 64 + cg * 16;
    float acc[16];
    #pragma unroll
    for (int jj = 0; jj < 16; ++jj) acc[jj] = 0.f;
    #pragma unroll 2
    for (int k = 0; k < 256; ++k){
        float a = s_agg[r * 260 + k];
        const float* wp = &Wc2[k * 256 + c0];
        #pragma unroll
        for (int jj = 0; jj < 16; ++jj) acc[jj] = fmaf(a, wp[jj], acc[jj]);
    }
    int row = blockIdx.x * 16 + r;
    #pragma unroll
    for (int jj = 0; jj < 16; ++jj) x2T[(size_t)(c0 + jj) * PM + row] = acc[jj];
    #pragma unroll
    for (int jj = 0; jj < 16; ++jj){
        float s1 = acc[jj], s2 = acc[jj] * acc[jj];
        s1 += __shfl_xor(s1, 1); s2 += __shfl_xor(s2, 1);
        s1 += __shfl_xor(s1, 2); s2 += __shfl_xor(s2, 2);
        s1 += __shfl_xor(s1, 4); s2 += __shfl_xor(s2, 4);
        s1 += __shfl_xor(s1, 8); s2 += __shfl_xor(s2, 8);
        if (r == 0){
            atomicAdd(&sums[c0 + jj], s1);
            atomicAdd(&sumsq[c0 + jj], s2);
        }
    }
}

__device__ __forceinline__ float block_sum1(float v1, float* s_red)
{
    #pragma unroll
    for (int m = 32; m; m >>= 1) v1 += __shfl_xor(v1, m);
    int w = threadIdx.x >> 6;
    if ((threadIdx.x & 63) == 0) s_red[w] = v1;
    __syncthreads();
    float t1 = s_red[0] + s_red[1] + s_red[2] + s_red[3];
    __syncthreads();
    return t1;
}

// layer-2 norm + lrelu + readout
__global__ __launch_bounds__(256) void norm2_kernel(
    const float* __restrict__ X, const float* __restrict__ sums,
    const float* __restrict__ sumsq, const float* __restrict__ g,
    const float* __restrict__ b, float* __restrict__ ro)
{
    __shared__ float s_red[4];
    int c = blockIdx.y;
    int r = blockIdx.x * 256 + threadIdx.x;
    float mu = sums[c] * (1.f / PM);
    float var = sumsq[c] * (1.f / PM) - mu * mu;
    float sc = g[c] * rsqrtf(var + EPSV);
    float h = 0.f;
    if (r < PM){
        float x = X[(size_t)c * PM + r];
        float y = sc * (x - mu) + b[c];
        h = (y >= 0.f) ? y : 0.01f * y;
    }
    float s = block_sum1(h, s_red);
    if (threadIdx.x == 0) atomicAdd(&ro[c], s);
}

__global__ __launch_bounds__(256) void final_kernel(
    const float* __restrict__ ro, const float* __restrict__ Wcls,
    float* __restrict__ out)
{
    __shared__ float s_part[256];
    int tid = threadIdx.x;
    int o = tid & 15, seg = tid >> 4;
    float pacc = 0.f;
    for (int j = seg * 32; j < seg * 32 + 32; ++j)
        pacc = fmaf(ro[j] * (1.f / PM), Wcls[j * OUT_C + o], pacc);
    s_part[tid] = pacc;
    __syncthreads();
    if (tid < OUT_C){
        float a = 0.f;
        #pragma unroll
        for (int s = 0; s < 16; ++s) a += s_part[s * 16 + tid];
        out[tid] = a;
    }
}

extern "C" void kernel_launch(void* const* d_in, const int* in_sizes, int n_in,
                              void* d_out, int out_size, void* d_ws, size_t ws_size,
                              hipStream_t stream) {
    const float* feats = (const float*)d_in[0];
    const int*   psrc  = (const int*)d_in[1];
    const int*   pdst  = (const int*)d_in[2];
    const float* pew   = (const float*)d_in[3];
    const int*   msrc  = (const int*)d_in[4];
    const int*   mdst  = (const int*)d_in[5];
    const float* mew   = (const float*)d_in[6];
    const float* W1    = (const float*)d_in[7];
    const float* g1    = (const float*)d_in[8];
    const float* b1    = (const float*)d_in[9];
    const float* W2    = (const float*)d_in[10];
    const float* g2    = (const float*)d_in[11];
    const float* b2    = (const float*)d_in[12];
    const float* We    = (const float*)d_in[13];
    const float* Wc1   = (const float*)d_in[14];
    const float* g3    = (const float*)d_in[15];
    const float* b3    = (const float*)d_in[16];
    const float* Wc2   = (const float*)d_in[17];
    const float* g4    = (const float*)d_in[18];
    const float* b4    = (const float*)d_in[19];
    const float* Wcls  = (const float*)d_in[20];
    float* out = (float*)d_out;
    float* ws  = (float*)d_ws;

    float*  degO  = ws + OFF_DEGO;
    float*  degI  = ws + OFF_DEGI;
    int*    offs  = (int*)(ws + OFF_OFFS);
    int*    cur   = (int*)(ws + OFF_CUR);
    int*    csrc  = (int*)(ws + OFF_CSRC);
    float*  csw   = ws + OFF_CSRW;
    float*  sums1 = ws + OFF_STATS;
    float*  sumsq1= ws + OFF_STATS + 256;
    float*  sums2 = ws + OFF_STATS + 512;
    float*  sumsq2= ws + OFF_STATS + 768;
    float*  ro    = ws + OFF_STATS + 1024;   // [512]
    ushort* W1s   = (ushort*)(ws + OFF_W1S);
    ushort* W2s   = (ushort*)(ws + OFF_W2S);
    float*  rbuf  = ws + OFF_RBUF;
    ushort* hRow  = (ushort*)(ws + OFF_RBUF);   // overlays rbuf (dead)
    float*  emb   = ws + OFF_EMB;
    float*  x1T   = ws + OFF_X1T;
    float*  x2T   = ws + OFF_X1T;               // overlays x1T (dead)

    hipMemsetAsync(degO, 0, 20032 * sizeof(float), stream);   // degO + degI
    hipMemsetAsync(cur,  0, 10016 * sizeof(int), stream);
    hipMemsetAsync(sums1,0, 1536 * sizeof(float), stream);    // stats + ro

    prep_kernel<<<128, 256, 0, stream>>>(W1, W2, W1s, W2s);
    patch_kernel<<<PM, 256, 0, stream>>>(feats, psrc, pdst, pew,
                                         W1s, g1, b1, W2s, g2, b2, rbuf);
    emb_kernel<<<625, 256, 0, stream>>>(rbuf, We, emb);
    deg_kernel<<<EM_N/256, 256, 0, stream>>>(msrc, mdst, degO, degI);
    scan_kernel<<<1, 256, 0, stream>>>(degI, offs);
    fill_kernel<<<EM_N/256, 256, 0, stream>>>(msrc, mdst, mew, degO, offs, cur, csrc, csw);
    ggemm1_kernel<<<625, 256, 0, stream>>>(emb, offs, csrc, csw, degI, Wc1,
                                           x1T, sums1, sumsq1);
    norm1t_kernel<<<dim3(157, 4), 256, 0, stream>>>(x1T, sums1, sumsq1, g3, b3, ro, hRow);
    ggemm2_kernel<<<625, 256, 0, stream>>>(hRow, offs, csrc, csw, degI, Wc2,
                                           x2T, sums2, sumsq2);
    norm2_kernel<<<dim3(40, 256), 256, 0, stream>>>(x2T, sums2, sumsq2, g4, b4, ro + 256);
    final_kernel<<<1, 256, 0, stream>>>(ro, Wcls, out);
}

// Round 5
// 921.613 us; speedup vs baseline: 1.4138x; 1.4138x over previous
//
#include <hip/hip_runtime.h>
#include <hip/hip_bf16.h>

#define PM    10000
#define NP_N  50
#define EP_N  200
#define EM_N  160000
#define OUT_C 16
#define EPSV  1e-5f

typedef __attribute__((ext_vector_type(8))) short short8;
typedef __attribute__((ext_vector_type(4))) float f32x4;

// workspace layout (float offsets)
#define OFF_DEGO   0          // [10016]
#define OFF_DEGI   10016
#define OFF_OFFS   20032      // int [10001]
#define OFF_CUR    30048      // int [10000]
#define OFF_CSRC   40064      // int [160000]
#define OFF_CSRW   200064     // f32 [160000]
#define OFF_STATS  360064     // sums1[256] sq1[256] sums2[256] sq2[256] ro[512]
#define OFF_W1S    361600     // 16384 bf16 = 8192 f-slots
#define OFF_W2S    369792
#define OFF_RBUF   377984     // f32 [PM][384] (dead after emb_kernel)
#define OFF_AGG1   377984     // f32 [PM][128] overlays rbuf   (dead after gemm1)
#define OFF_AGG2   377984     // bf16 [PM][256] overlays agg1  (gather2 output)
#define OFF_X1     1657984    // f32 [PM][256] overlays rbuf tail (dead after norm1)
#define OFF_X2     1657984    // f32 [PM][256] overlays x1
#define OFF_EMB    4217984    // f32 [PM][128] (dead after gather1)
#define OFF_HROW   4217984    // bf16 [PM][256] overlays emb

__device__ __forceinline__ ushort f2bf(float f){
    __hip_bfloat16 h = __float2bfloat16(f);
    return *reinterpret_cast<ushort*>(&h);
}
__device__ __forceinline__ uint pack2(float a, float b){
    return (uint)f2bf(a) | ((uint)f2bf(b) << 16);
}

// ---------------------------------------------------------------------------
// prep: swizzle W1 [64][256] and W2 [256][64] into bf16 MFMA B-fragment order
// ---------------------------------------------------------------------------
__global__ __launch_bounds__(256) void prep_kernel(
    const float* __restrict__ W1, const float* __restrict__ W2,
    ushort* __restrict__ W1s, ushort* __restrict__ W2s)
{
    int gid = blockIdx.x * 256 + threadIdx.x;
    if (gid < 16384){
        int j = gid & 7, l = (gid >> 3) & 63, ki = (gid >> 9) & 1, ct = gid >> 10;
        int k = ki * 32 + ((l >> 4) << 3) + j;
        int n = ct * 16 + (l & 15);
        W1s[gid] = f2bf(W1[k * 256 + n]);
    } else {
        int g = gid - 16384;
        int j = g & 7, l = (g >> 3) & 63, ki = (g >> 9) & 7, ct = g >> 12;
        int k = ki * 32 + ((l >> 4) << 3) + j;
        int n = ct * 16 + (l & 15);
        W2s[g] = f2bf(W2[k * 64 + n]);
    }
}

// ---------------------------------------------------------------------------
// Patch embedder: all-MFMA, one block (4 waves) per patch. Writes r[384].
// ---------------------------------------------------------------------------
__global__ __launch_bounds__(256, 5) void patch_kernel(
    const float* __restrict__ feats, const int* __restrict__ esrc,
    const int* __restrict__ edst, const float* __restrict__ eew,
    const ushort* __restrict__ W1s, const float* __restrict__ g1,
    const float* __restrict__ b1, const ushort* __restrict__ W2s,
    const float* __restrict__ g2, const float* __restrict__ b2,
    float* __restrict__ rbuf)
{
    __shared__ __align__(16) char smem[29184];
    float* s_A  = (float*)smem;              // [64][68] f32 (dies after frag extract)
    char*  s_h1 = smem;                      // bf16 half-h1, 64 rows x 272B, swizzled
    char*  s_G1 = smem + 17408;              // bf16 G1, 64 rows x 144B, swizzled
    float* s_deg = (float*)(smem + 26624);   // 128
    float* s_rs  = (float*)(smem + 27136);   // 128
    float* s_r   = (float*)(smem + 27648);   // 384

    const int tid  = threadIdx.x;
    const int p    = blockIdx.x;
    const int lane = tid & 63;
    const int wv   = tid >> 6;
    const int lnlo = lane & 15;
    const int lghi = lane >> 4;

    float fl[2][8];
    {
        const float* fbase = feats + (size_t)p * 3200 + wv * 16 + lnlo;
        #pragma unroll
        for (int ki = 0; ki < 2; ++ki)
            #pragma unroll
            for (int j = 0; j < 8; ++j){
                int s = ki * 32 + lghi * 8 + j;
                int sc = (s < NP_N) ? s : (NP_N - 1);
                fl[ki][j] = fbase[sc * 64];
            }
    }
    int es = 0, ed = 0; float ewt = 0.f;
    if (tid < EP_N){
        es  = esrc[p * EP_N + tid];
        ed  = edst[p * EP_N + tid];
        ewt = eew[p * EP_N + tid];
    }
    for (int i = tid; i < 1088; i += 256)
        *(float4*)&s_A[i * 4] = make_float4(0.f, 0.f, 0.f, 0.f);
    if (tid < 128) s_deg[tid] = 0.f;
    __syncthreads();
    if (tid < EP_N){
        atomicAdd(&s_deg[es], 1.f);
        atomicAdd(&s_deg[64 + ed], 1.f);
    }
    float r0s = 0.f;
    #pragma unroll
    for (int ki = 0; ki < 2; ++ki)
        #pragma unroll
        for (int j = 0; j < 8; ++j)
            r0s += (ki * 32 + lghi * 8 + j < NP_N) ? fl[ki][j] : 0.f;
    r0s += __shfl_xor(r0s, 16); r0s += __shfl_xor(r0s, 32);
    __syncthreads();
    if (tid < 128) s_rs[tid] = rsqrtf(fmaxf(s_deg[tid], 1.f));
    if (lghi == 0) s_r[wv * 16 + lnlo] = r0s * 0.02f;
    short8 fbf[2];
    #pragma unroll
    for (int ki = 0; ki < 2; ++ki)
        #pragma unroll
        for (int j = 0; j < 8; ++j)
            fbf[ki][j] = (short)f2bf(fl[ki][j]);
    __syncthreads();
    if (tid < EP_N)
        atomicAdd(&s_A[ed * 68 + es], ewt * s_rs[es] * s_rs[64 + ed]);
    __syncthreads();
    short8 afr[4][2];
    #pragma unroll
    for (int rt = 0; rt < 4; ++rt)
        #pragma unroll
        for (int ki = 0; ki < 2; ++ki){
            int row = rt * 16 + lnlo, k0 = ki * 32 + lghi * 8;
            float4 f0 = *(const float4*)&s_A[row * 68 + k0];
            float4 f1 = *(const float4*)&s_A[row * 68 + k0 + 4];
            short8 sv;
            sv[0] = (short)f2bf(f0.x); sv[1] = (short)f2bf(f0.y);
            sv[2] = (short)f2bf(f0.z); sv[3] = (short)f2bf(f0.w);
            sv[4] = (short)f2bf(f1.x); sv[5] = (short)f2bf(f1.y);
            sv[6] = (short)f2bf(f1.z); sv[7] = (short)f2bf(f1.w);
            afr[rt][ki] = sv;
        }
    f32x4 cacc[4];
    #pragma unroll
    for (int rt = 0; rt < 4; ++rt) cacc[rt] = (f32x4){0.f,0.f,0.f,0.f};
    #pragma unroll
    for (int rt = 0; rt < 4; ++rt){
        cacc[rt] = __builtin_amdgcn_mfma_f32_16x16x32_bf16(afr[rt][0], fbf[0], cacc[rt], 0,0,0);
        cacc[rt] = __builtin_amdgcn_mfma_f32_16x16x32_bf16(afr[rt][1], fbf[1], cacc[rt], 0,0,0);
    }
    #pragma unroll
    for (int rt = 0; rt < 4; ++rt)
        #pragma unroll
        for (int e = 0; e < 4; ++e){
            int row = rt * 16 + lghi * 4 + e;
            int col = wv * 16 + lnlo;
            *(ushort*)(s_G1 + row * 144 + ((col * 2) ^ ((row & 8) << 2))) = f2bf(cacc[rt][e]);
        }
    __syncthreads();

    f32x4 zacc[4];
    #pragma unroll
    for (int rt = 0; rt < 4; ++rt) zacc[rt] = (f32x4){0.f,0.f,0.f,0.f};

    for (int h = 0; h < 2; ++h){
        short8 ga[4][2];
        #pragma unroll
        for (int rt = 0; rt < 4; ++rt)
            #pragma unroll
            for (int ki = 0; ki < 2; ++ki){
                int row = rt * 16 + lnlo, k0 = ki * 32 + lghi * 8;
                ga[rt][ki] = *(const short8*)(s_G1 + row * 144 + ((k0 * 2) ^ ((row & 8) << 2)));
            }
        #pragma unroll
        for (int ctl = 0; ctl < 2; ++ctl){
            int ctg = h * 8 + wv * 2 + ctl;
            short8 wb0 = *(const short8*)&W1s[((ctg * 2 + 0) * 64 + lane) * 8];
            short8 wb1 = *(const short8*)&W1s[((ctg * 2 + 1) * 64 + lane) * 8];
            f32x4 m[4];
            #pragma unroll
            for (int rt = 0; rt < 4; ++rt) m[rt] = (f32x4){0.f,0.f,0.f,0.f};
            #pragma unroll
            for (int rt = 0; rt < 4; ++rt){
                m[rt] = __builtin_amdgcn_mfma_f32_16x16x32_bf16(ga[rt][0], wb0, m[rt], 0,0,0);
                m[rt] = __builtin_amdgcn_mfma_f32_16x16x32_bf16(ga[rt][1], wb1, m[rt], 0,0,0);
            }
            float s1 = 0.f, s2 = 0.f;
            #pragma unroll
            for (int rt = 0; rt < 4; ++rt)
                #pragma unroll
                for (int e = 0; e < 4; ++e){ float x = m[rt][e]; s1 += x; s2 += x*x; }
            s1 += __shfl_xor(s1, 16); s1 += __shfl_xor(s1, 32);
            s2 += __shfl_xor(s2, 16); s2 += __shfl_xor(s2, 32);
            float mu = s1 * 0.02f;
            float var = s2 * 0.02f - mu * mu;
            float rinv = rsqrtf(var + EPSV);
            int jg = ctg * 16 + lnlo;
            float sc = g1[jg] * rinv;
            float sh = b1[jg] - mu * sc;
            float r1p = 0.f;
            int jl = (wv * 2 + ctl) * 16 + lnlo;
            #pragma unroll
            for (int rt = 0; rt < 4; ++rt)
                #pragma unroll
                for (int e = 0; e < 4; ++e){
                    int row = rt * 16 + lghi * 4 + e;
                    float y = m[rt][e] * sc + sh;
                    float hh = (y >= 0.f) ? y : 0.01f * y;
                    hh = (row < NP_N) ? hh : 0.f;
                    r1p += hh;
                    *(ushort*)(s_h1 + row * 272 + ((jl * 2) ^ ((row & 8) << 2))) = f2bf(hh);
                }
            r1p += __shfl_xor(r1p, 16); r1p += __shfl_xor(r1p, 32);
            if (lghi == 0) s_r[64 + jg] = r1p * 0.02f;
        }
        __syncthreads();
        #pragma unroll
        for (int kil = 0; kil < 4; ++kil){
            short8 wb2 = *(const short8*)&W2s[((wv * 8 + h * 4 + kil) * 64 + lane) * 8];
            #pragma unroll
            for (int rt = 0; rt < 4; ++rt){
                int row = rt * 16 + lnlo, kl = kil * 32 + lghi * 8;
                short8 a = *(const short8*)(s_h1 + row * 272 + ((kl * 2) ^ ((row & 8) << 2)));
                zacc[rt] = __builtin_amdgcn_mfma_f32_16x16x32_bf16(a, wb2, zacc[rt], 0,0,0);
            }
        }
        __syncthreads();
    }

    uint pk[4][2];
    #pragma unroll
    for (int rt = 0; rt < 4; ++rt){
        pk[rt][0] = pack2(zacc[rt][0], zacc[rt][1]);
        pk[rt][1] = pack2(zacc[rt][2], zacc[rt][3]);
    }
    bool hi = (lghi >= 2);
    int lane_lo = (((lghi * 2 + 0) & 3) << 4) + lnlo;
    int lane_hi = (((lghi * 2 + 1) & 3) << 4) + lnlo;
    short8 zb[2];
    #pragma unroll
    for (int ki = 0; ki < 2; ++ki){
        uint sA = hi ? pk[ki*2+1][0] : pk[ki*2][0];
        uint sB = hi ? pk[ki*2+1][1] : pk[ki*2][1];
        uint w0 = (uint)__shfl((int)sA, lane_lo, 64);
        uint w1 = (uint)__shfl((int)sB, lane_lo, 64);
        uint w2 = (uint)__shfl((int)sA, lane_hi, 64);
        uint w3 = (uint)__shfl((int)sB, lane_hi, 64);
        short8 z;
        z[0] = (short)(w0 & 0xffff); z[1] = (short)(w0 >> 16);
        z[2] = (short)(w1 & 0xffff); z[3] = (short)(w1 >> 16);
        z[4] = (short)(w2 & 0xffff); z[5] = (short)(w2 >> 16);
        z[6] = (short)(w3 & 0xffff); z[7] = (short)(w3 >> 16);
        zb[ki] = z;
    }
    f32x4 oacc[4];
    #pragma unroll
    for (int rt = 0; rt < 4; ++rt) oacc[rt] = (f32x4){0.f,0.f,0.f,0.f};
    #pragma unroll
    for (int rt = 0; rt < 4; ++rt){
        oacc[rt] = __builtin_amdgcn_mfma_f32_16x16x32_bf16(afr[rt][0], zb[0], oacc[rt], 0,0,0);
        oacc[rt] = __builtin_amdgcn_mfma_f32_16x16x32_bf16(afr[rt][1], zb[1], oacc[rt], 0,0,0);
    }
    {
        float s1 = 0.f, s2 = 0.f;
        #pragma unroll
        for (int rt = 0; rt < 4; ++rt)
            #pragma unroll
            for (int e = 0; e < 4; ++e){ float x = oacc[rt][e]; s1 += x; s2 += x*x; }
        s1 += __shfl_xor(s1, 16); s1 += __shfl_xor(s1, 32);
        s2 += __shfl_xor(s2, 16); s2 += __shfl_xor(s2, 32);
        float mu = s1 * 0.02f;
        float var = s2 * 0.02f - mu * mu;
        float rinv = rsqrtf(var + EPSV);
        int c2 = wv * 16 + lnlo;
        float sc = g2[c2] * rinv;
        float sh = b2[c2] - mu * sc;
        float r2p = 0.f;
        #pragma unroll
        for (int rt = 0; rt < 4; ++rt)
            #pragma unroll
            for (int e = 0; e < 4; ++e){
                int row = rt * 16 + lghi * 4 + e;
                float y = oacc[rt][e] * sc + sh;
                float hh = (y >= 0.f) ? y : 0.01f * y;
                r2p += (row < NP_N) ? hh : 0.f;
            }
        r2p += __shfl_xor(r2p, 16); r2p += __shfl_xor(r2p, 32);
        if (lghi == 0) s_r[320 + c2] = r2p * 0.02f;
    }
    __syncthreads();
    if (tid < 96)
        *(float4*)&rbuf[(size_t)p * 384 + tid * 4] = *(const float4*)&s_r[tid * 4];
}

// ---------------------------------------------------------------------------
// emb = InstanceNorm(R @ We) + lrelu
// ---------------------------------------------------------------------------
__global__ __launch_bounds__(256) void emb_kernel(
    const float* __restrict__ rbuf, const float* __restrict__ We,
    float* __restrict__ emb)
{
    __shared__ float s_R[16 * 388];
    int tid = threadIdx.x;
    int rb = blockIdx.x * 16;
    for (int i = tid; i < 1536; i += 256){
        int r = i / 96, q = i - r * 96;
        *(float4*)&s_R[r * 388 + q * 4] =
            *(const float4*)&rbuf[(size_t)(rb + r) * 384 + q * 4];
    }
    __syncthreads();
    int r = tid >> 4, c0 = (tid & 15) * 8;
    float acc[8];
    #pragma unroll
    for (int j = 0; j < 8; ++j) acc[j] = 0.f;
    for (int k = 0; k < 384; ++k){
        float a = s_R[r * 388 + k];
        const float* wp = &We[k * 128 + c0];
        #pragma unroll
        for (int j = 0; j < 8; ++j) acc[j] = fmaf(a, wp[j], acc[j]);
    }
    float s1 = 0.f, s2 = 0.f;
    #pragma unroll
    for (int j = 0; j < 8; ++j){ s1 += acc[j]; s2 += acc[j] * acc[j]; }
    s1 += __shfl_xor(s1, 1); s2 += __shfl_xor(s2, 1);
    s1 += __shfl_xor(s1, 2); s2 += __shfl_xor(s2, 2);
    s1 += __shfl_xor(s1, 4); s2 += __shfl_xor(s2, 4);
    s1 += __shfl_xor(s1, 8); s2 += __shfl_xor(s2, 8);
    float mu = s1 * (1.f / 128.f);
    float var = s2 * (1.f / 128.f) - mu * mu;
    float rinv = rsqrtf(var + EPSV);
    float o[8];
    #pragma unroll
    for (int j = 0; j < 8; ++j){
        float y = (acc[j] - mu) * rinv;
        o[j] = (y >= 0.f) ? y : 0.01f * y;
    }
    float* op = &emb[(size_t)(rb + r) * 128 + c0];
    *(float4*)op = make_float4(o[0], o[1], o[2], o[3]);
    *(float4*)(op + 4) = make_float4(o[4], o[5], o[6], o[7]);
}

// ---------------------------------------------------------------------------
// Mesh CSR build
// ---------------------------------------------------------------------------
__global__ __launch_bounds__(256) void deg_kernel(
    const int* __restrict__ msrc, const int* __restrict__ mdst,
    float* __restrict__ degO, float* __restrict__ degI)
{
    int e = blockIdx.x * 256 + threadIdx.x;
    if (e < EM_N){
        atomicAdd(&degO[msrc[e]], 1.f);
        atomicAdd(&degI[mdst[e]], 1.f);
    }
}

__global__ __launch_bounds__(256) void scan_kernel(
    const float* __restrict__ degI, int* __restrict__ offs)
{
    __shared__ int s_sc[256];
    int t = threadIdx.x;
    int sum = 0;
    for (int k = 0; k < 40; ++k){ int i = t * 40 + k; if (i < PM) sum += (int)degI[i]; }
    s_sc[t] = sum;
    __syncthreads();
    for (int off = 1; off < 256; off <<= 1){
        int v = (t >= off) ? s_sc[t - off] : 0;
        __syncthreads();
        s_sc[t] += v;
        __syncthreads();
    }
    int run = s_sc[t] - sum;
    for (int k = 0; k < 40; ++k){
        int i = t * 40 + k;
        if (i < PM){ offs[i] = run; run += (int)degI[i]; }
    }
    if (t == 255) offs[PM] = s_sc[255];
}

__global__ __launch_bounds__(256) void fill_kernel(
    const int* __restrict__ msrc, const int* __restrict__ mdst,
    const float* __restrict__ mew, const float* __restrict__ degO,
    const int* __restrict__ offs, int* __restrict__ cur,
    int* __restrict__ csrc, float* __restrict__ csw)
{
    int e = blockIdx.x * 256 + threadIdx.x;
    if (e < EM_N){
        int d = mdst[e], s = msrc[e];
        int pos = atomicAdd(&cur[d], 1);
        int idx = offs[d] + pos;
        csrc[idx] = s;
        csw[idx] = mew[e] * rsqrtf(fmaxf(degO[s], 1.f));
    }
}

// ---------------------------------------------------------------------------
// gather1: node-per-wave. agg1[d][128] = rsI(d) * sum_e csw * emb[src]
// grid 2500 x 256 (4 nodes/block)
// ---------------------------------------------------------------------------
__global__ __launch_bounds__(256) void gather1_kernel(
    const float* __restrict__ emb, const int* __restrict__ offs,
    const int* __restrict__ csrc, const float* __restrict__ csw,
    const float* __restrict__ degI, float* __restrict__ agg1)
{
    int lane = threadIdx.x & 63, wv = threadIdx.x >> 6;
    int d = blockIdx.x * 4 + wv;
    int e0 = offs[d], e1 = offs[d + 1];
    float a0 = 0.f, a1 = 0.f;
    const float* ebase = emb + lane * 2;
    int e = e0;
    for (; e + 2 <= e1; e += 2){
        int s0 = csrc[e], s1 = csrc[e + 1];
        float w0 = csw[e], w1 = csw[e + 1];
        float2 v0 = *(const float2*)(ebase + (size_t)s0 * 128);
        float2 v1 = *(const float2*)(ebase + (size_t)s1 * 128);
        a0 = fmaf(v0.x, w0, a0); a1 = fmaf(v0.y, w0, a1);
        a0 = fmaf(v1.x, w1, a0); a1 = fmaf(v1.y, w1, a1);
    }
    if (e < e1){
        int s0 = csrc[e]; float w0 = csw[e];
        float2 v0 = *(const float2*)(ebase + (size_t)s0 * 128);
        a0 = fmaf(v0.x, w0, a0); a1 = fmaf(v0.y, w0, a1);
    }
    float rs = rsqrtf(fmaxf(degI[d], 1.f));
    *(float2*)&agg1[(size_t)d * 128 + lane * 2] = make_float2(a0 * rs, a1 * rs);
}

// ---------------------------------------------------------------------------
// gemm1: x1[row][c] = sum_k agg1[row][k] * Wc1[k][c], fused col stats.
// grid (157, 4); block = 64 rows x 64 cols
// ---------------------------------------------------------------------------
__global__ __launch_bounds__(256) void gemm1_kernel(
    const float* __restrict__ agg1, const float* __restrict__ Wc1,
    float* __restrict__ x1, float* __restrict__ sums, float* __restrict__ sumsq)
{
    __shared__ float s_A[64 * 129];
    int tid = threadIdx.x, lane = tid & 63, w = tid >> 6;
    int rb = blockIdx.x * 64;
    for (int i = tid; i < 2048; i += 256){
        int r = i >> 5, q = i & 31;
        float4 v = (rb + r < PM)
            ? *(const float4*)&agg1[(size_t)(rb + r) * 128 + q * 4]
            : make_float4(0.f, 0.f, 0.f, 0.f);
        float* dst = &s_A[r * 129 + q * 4];
        dst[0] = v.x; dst[1] = v.y; dst[2] = v.z; dst[3] = v.w;
    }
    __syncthreads();
    int c0 = blockIdx.y * 64 + w * 16;
    float acc[16];
    #pragma unroll
    for (int jj = 0; jj < 16; ++jj) acc[jj] = 0.f;
    #pragma unroll 4
    for (int k = 0; k < 128; ++k){
        float a = s_A[lane * 129 + k];
        const float* wp = &Wc1[k * 256 + c0];
        #pragma unroll
        for (int jj = 0; jj < 16; ++jj) acc[jj] = fmaf(a, wp[jj], acc[jj]);
    }
    int row = rb + lane;
    if (row < PM){
        #pragma unroll
        for (int q = 0; q < 4; ++q)
            *(float4*)&x1[(size_t)row * 256 + c0 + q * 4] =
                make_float4(acc[q*4], acc[q*4+1], acc[q*4+2], acc[q*4+3]);
    }
    #pragma unroll
    for (int jj = 0; jj < 16; ++jj){
        float s1 = acc[jj], s2 = acc[jj] * acc[jj];
        #pragma unroll
        for (int m = 32; m; m >>= 1){ s1 += __shfl_xor(s1, m); s2 += __shfl_xor(s2, m); }
        if (lane == 0){
            atomicAdd(&sums[c0 + jj], s1);
            atomicAdd(&sumsq[c0 + jj], s2);
        }
    }
}

// ---------------------------------------------------------------------------
// norm1: row-major norm + lrelu -> hRow bf16, fused readout. grid 625
// ---------------------------------------------------------------------------
__global__ __launch_bounds__(256) void norm1_kernel(
    const float* __restrict__ x1, const float* __restrict__ sums,
    const float* __restrict__ sumsq, const float* __restrict__ g,
    const float* __restrict__ b, float* __restrict__ ro, ushort* __restrict__ hRow)
{
    int tid = threadIdx.x;
    int rb = blockIdx.x * 16;
    float mu = sums[tid] * (1.f / PM);
    float var = sumsq[tid] * (1.f / PM) - mu * mu;
    float sc = g[tid] * rsqrtf(var + EPSV);
    float sh = b[tid] - mu * sc;
    float lsum = 0.f;
    #pragma unroll 4
    for (int i = 0; i < 16; ++i){
        float x = x1[(size_t)(rb + i) * 256 + tid];
        float y = sc * x + sh;
        float h = (y >= 0.f) ? y : 0.01f * y;
        lsum += h;
        hRow[(size_t)(rb + i) * 256 + tid] = f2bf(h);
    }
    atomicAdd(&ro[tid], lsum);
}

// ---------------------------------------------------------------------------
// gather2: node-per-wave over hRow bf16. agg2 bf16 [PM][256]. grid 2500
// ---------------------------------------------------------------------------
__global__ __launch_bounds__(256) void gather2_kernel(
    const ushort* __restrict__ hRow, const int* __restrict__ offs,
    const int* __restrict__ csrc, const float* __restrict__ csw,
    const float* __restrict__ degI, uint* __restrict__ agg2)
{
    int lane = threadIdx.x & 63, wv = threadIdx.x >> 6;
    int d = blockIdx.x * 4 + wv;
    int e0 = offs[d], e1 = offs[d + 1];
    float a0 = 0.f, a1 = 0.f, a2 = 0.f, a3 = 0.f;
    const ushort* hbase = hRow + lane * 4;
    int e = e0;
    for (; e + 2 <= e1; e += 2){
        int s0 = csrc[e], s1 = csrc[e + 1];
        float w0 = csw[e], w1 = csw[e + 1];
        uint2 q0 = *(const uint2*)(hbase + (size_t)s0 * 256);
        uint2 q1 = *(const uint2*)(hbase + (size_t)s1 * 256);
        a0 = fmaf(__uint_as_float(q0.x << 16), w0, a0);
        a1 = fmaf(__uint_as_float(q0.x & 0xffff0000u), w0, a1);
        a2 = fmaf(__uint_as_float(q0.y << 16), w0, a2);
        a3 = fmaf(__uint_as_float(q0.y & 0xffff0000u), w0, a3);
        a0 = fmaf(__uint_as_float(q1.x << 16), w1, a0);
        a1 = fmaf(__uint_as_float(q1.x & 0xffff0000u), w1, a1);
        a2 = fmaf(__uint_as_float(q1.y << 16), w1, a2);
        a3 = fmaf(__uint_as_float(q1.y & 0xffff0000u), w1, a3);
    }
    if (e < e1){
        int s0 = csrc[e]; float w0 = csw[e];
        uint2 q0 = *(const uint2*)(hbase + (size_t)s0 * 256);
        a0 = fmaf(__uint_as_float(q0.x << 16), w0, a0);
        a1 = fmaf(__uint_as_float(q0.x & 0xffff0000u), w0, a1);
        a2 = fmaf(__uint_as_float(q0.y << 16), w0, a2);
        a3 = fmaf(__uint_as_float(q0.y & 0xffff0000u), w0, a3);
    }
    float rs = rsqrtf(fmaxf(degI[d], 1.f));
    uint2 o;
    o.x = pack2(a0 * rs, a1 * rs);
    o.y = pack2(a2 * rs, a3 * rs);
    *(uint2*)&agg2[(size_t)d * 128 + lane * 2] = o;
}

// ---------------------------------------------------------------------------
// gemm2: x2[row][c] = sum_k agg2[row][k] * Wc2[k][c] (K=256 bf16), fused stats
// grid (157, 4)
// ---------------------------------------------------------------------------
__global__ __launch_bounds__(256) void gemm2_kernel(
    const uint* __restrict__ agg2, const float* __restrict__ Wc2,
    float* __restrict__ x2, float* __restrict__ sums, float* __restrict__ sumsq)
{
    __shared__ uint s_A[64 * 129];
    int tid = threadIdx.x, lane = tid & 63, w = tid >> 6;
    int rb = blockIdx.x * 64;
    for (int i = tid; i < 4096; i += 256){
        int r = i >> 6, q = i & 63;
        uint2 v = (rb + r < PM)
            ? *(const uint2*)&agg2[(size_t)(rb + r) * 128 + q * 2]
            : make_uint2(0u, 0u);
        s_A[r * 129 + q * 2]     = v.x;
        s_A[r * 129 + q * 2 + 1] = v.y;
    }
    __syncthreads();
    int c0 = blockIdx.y * 64 + w * 16;
    float acc[16];
    #pragma unroll
    for (int jj = 0; jj < 16; ++jj) acc[jj] = 0.f;
    #pragma unroll 2
    for (int q = 0; q < 128; ++q){
        uint u = s_A[lane * 129 + q];
        float alo = __uint_as_float(u << 16);
        float ahi = __uint_as_float(u & 0xffff0000u);
        const float* wp0 = &Wc2[(2 * q) * 256 + c0];
        const float* wp1 = &Wc2[(2 * q + 1) * 256 + c0];
        #pragma unroll
        for (int jj = 0; jj < 16; ++jj){
            acc[jj] = fmaf(alo, wp0[jj], acc[jj]);
            acc[jj] = fmaf(ahi, wp1[jj], acc[jj]);
        }
    }
    int row = rb + lane;
    if (row < PM){
        #pragma unroll
        for (int q = 0; q < 4; ++q)
            *(float4*)&x2[(size_t)row * 256 + c0 + q * 4] =
                make_float4(acc[q*4], acc[q*4+1], acc[q*4+2], acc[q*4+3]);
    }
    #pragma unroll
    for (int jj = 0; jj < 16; ++jj){
        float s1 = acc[jj], s2 = acc[jj] * acc[jj];
        #pragma unroll
        for (int m = 32; m; m >>= 1){ s1 += __shfl_xor(s1, m); s2 += __shfl_xor(s2, m); }
        if (lane == 0){
            atomicAdd(&sums[c0 + jj], s1);
            atomicAdd(&sumsq[c0 + jj], s2);
        }
    }
}

// ---------------------------------------------------------------------------
// norm2: row-major norm + lrelu + readout (no store). grid 625
// ---------------------------------------------------------------------------
__global__ __launch_bounds__(256) void norm2_kernel(
    const float* __restrict__ x2, const float* __restrict__ sums,
    const float* __restrict__ sumsq, const float* __restrict__ g,
    const float* __restrict__ b, float* __restrict__ ro)
{
    int tid = threadIdx.x;
    int rb = blockIdx.x * 16;
    float mu = sums[tid] * (1.f / PM);
    float var = sumsq[tid] * (1.f / PM) - mu * mu;
    float sc = g[tid] * rsqrtf(var + EPSV);
    float sh = b[tid] - mu * sc;
    float lsum = 0.f;
    #pragma unroll 4
    for (int i = 0; i < 16; ++i){
        float x = x2[(size_t)(rb + i) * 256 + tid];
        float y = sc * x + sh;
        lsum += (y >= 0.f) ? y : 0.01f * y;
    }
    atomicAdd(&ro[tid], lsum);
}

__global__ __launch_bounds__(256) void final_kernel(
    const float* __restrict__ ro, const float* __restrict__ Wcls,
    float* __restrict__ out)
{
    __shared__ float s_part[256];
    int tid = threadIdx.x;
    int o = tid & 15, seg = tid >> 4;
    float pacc = 0.f;
    for (int j = seg * 32; j < seg * 32 + 32; ++j)
        pacc = fmaf(ro[j] * (1.f / PM), Wcls[j * OUT_C + o], pacc);
    s_part[tid] = pacc;
    __syncthreads();
    if (tid < OUT_C){
        float a = 0.f;
        #pragma unroll
        for (int s = 0; s < 16; ++s) a += s_part[s * 16 + tid];
        out[tid] = a;
    }
}

extern "C" void kernel_launch(void* const* d_in, const int* in_sizes, int n_in,
                              void* d_out, int out_size, void* d_ws, size_t ws_size,
                              hipStream_t stream) {
    const float* feats = (const float*)d_in[0];
    const int*   psrc  = (const int*)d_in[1];
    const int*   pdst  = (const int*)d_in[2];
    const float* pew   = (const float*)d_in[3];
    const int*   msrc  = (const int*)d_in[4];
    const int*   mdst  = (const int*)d_in[5];
    const float* mew   = (const float*)d_in[6];
    const float* W1    = (const float*)d_in[7];
    const float* g1    = (const float*)d_in[8];
    const float* b1    = (const float*)d_in[9];
    const float* W2    = (const float*)d_in[10];
    const float* g2    = (const float*)d_in[11];
    const float* b2    = (const float*)d_in[12];
    const float* We    = (const float*)d_in[13];
    const float* Wc1   = (const float*)d_in[14];
    const float* g3    = (const float*)d_in[15];
    const float* b3    = (const float*)d_in[16];
    const float* Wc2   = (const float*)d_in[17];
    const float* g4    = (const float*)d_in[18];
    const float* b4    = (const float*)d_in[19];
    const float* Wcls  = (const float*)d_in[20];
    float* out = (float*)d_out;
    float* ws  = (float*)d_ws;

    float*  degO  = ws + OFF_DEGO;
    float*  degI  = ws + OFF_DEGI;
    int*    offs  = (int*)(ws + OFF_OFFS);
    int*    cur   = (int*)(ws + OFF_CUR);
    int*    csrc  = (int*)(ws + OFF_CSRC);
    float*  csw   = ws + OFF_CSRW;
    float*  sums1 = ws + OFF_STATS;
    float*  sumsq1= ws + OFF_STATS + 256;
    float*  sums2 = ws + OFF_STATS + 512;
    float*  sumsq2= ws + OFF_STATS + 768;
    float*  ro    = ws + OFF_STATS + 1024;   // [512]
    ushort* W1s   = (ushort*)(ws + OFF_W1S);
    ushort* W2s   = (ushort*)(ws + OFF_W2S);
    float*  rbuf  = ws + OFF_RBUF;
    float*  agg1  = ws + OFF_AGG1;           // overlays rbuf (dead after emb)
    uint*   agg2  = (uint*)(ws + OFF_AGG2);  // overlays agg1 (dead after gemm1)
    float*  x1    = ws + OFF_X1;
    float*  x2    = ws + OFF_X2;             // overlays x1 (dead after norm1)
    float*  emb   = ws + OFF_EMB;
    ushort* hRow  = (ushort*)(ws + OFF_HROW); // overlays emb (dead after gather1)

    hipMemsetAsync(degO, 0, 20032 * sizeof(float), stream);   // degO + degI
    hipMemsetAsync(cur,  0, 10016 * sizeof(int), stream);
    hipMemsetAsync(sums1,0, 1536 * sizeof(float), stream);    // stats + ro

    prep_kernel<<<128, 256, 0, stream>>>(W1, W2, W1s, W2s);
    patch_kernel<<<PM, 256, 0, stream>>>(feats, psrc, pdst, pew,
                                         W1s, g1, b1, W2s, g2, b2, rbuf);
    emb_kernel<<<625, 256, 0, stream>>>(rbuf, We, emb);
    deg_kernel<<<EM_N/256, 256, 0, stream>>>(msrc, mdst, degO, degI);
    scan_kernel<<<1, 256, 0, stream>>>(degI, offs);
    fill_kernel<<<EM_N/256, 256, 0, stream>>>(msrc, mdst, mew, degO, offs, cur, csrc, csw);
    gather1_kernel<<<2500, 256, 0, stream>>>(emb, offs, csrc, csw, degI, agg1);
    gemm1_kernel<<<dim3(157, 4), 256, 0, stream>>>(agg1, Wc1, x1, sums1, sumsq1);
    norm1_kernel<<<625, 256, 0, stream>>>(x1, sums1, sumsq1, g3, b3, ro, hRow);
    gather2_kernel<<<2500, 256, 0, stream>>>(hRow, offs, csrc, csw, degI, agg2);
    gemm2_kernel<<<dim3(157, 4), 256, 0, stream>>>(agg2, Wc2, x2, sums2, sumsq2);
    norm2_kernel<<<625, 256, 0, stream>>>(x2, sums2, sumsq2, g4, b4, ro + 256);
    final_kernel<<<1, 256, 0, stream>>>(ro, Wcls, out);
}

// Round 6
// 857.994 us; speedup vs baseline: 1.5187x; 1.0741x over previous
//
#include <hip/hip_runtime.h>
#include <hip/hip_bf16.h>

#define PM    10000
#define NP_N  50
#define EP_N  200
#define EM_N  160000
#define OUT_C 16
#define EPSV  1e-5f

typedef __attribute__((ext_vector_type(8))) short short8;
typedef __attribute__((ext_vector_type(4))) float f32x4;

// workspace layout (float offsets)
#define OFF_DEGO   0          // [10016]
#define OFF_DEGI   10016
#define OFF_OFFS   20032      // int [10001]
#define OFF_CUR    30048      // int [10000]
#define OFF_CSRC   40064      // int [160000]
#define OFF_CSRW   200064     // f32 [160000]
#define OFF_STATS  360064     // sums1[256] sq1[256] sums2[256] sq2[256] ro[512]
#define OFF_W1S    361600     // 16384 bf16 = 8192 f-slots
#define OFF_W2S    369792
#define OFF_RBUF   377984     // f32 [PM][384] (dead after emb_kernel)
#define OFF_AGG1   377984     // f32 [PM][128] overlays rbuf   (dead after gemm1)
#define OFF_AGG2   377984     // bf16 [PM][256] overlays agg1  (gather2 output)
#define OFF_X1     1657984    // f32 [PM][256] overlays rbuf tail (dead after norm1)
#define OFF_X2     1657984    // f32 [PM][256] overlays x1
#define OFF_EMB    4217984    // f32 [PM][128] (dead after gather1)
#define OFF_HROW   4217984    // bf16 [PM][256] overlays emb

__device__ __forceinline__ ushort f2bf(float f){
    __hip_bfloat16 h = __float2bfloat16(f);
    return *reinterpret_cast<ushort*>(&h);
}
__device__ __forceinline__ uint pack2(float a, float b){
    return (uint)f2bf(a) | ((uint)f2bf(b) << 16);
}

// ---------------------------------------------------------------------------
// prep: swizzle W1 [64][256] and W2 [256][64] into bf16 MFMA B-fragment order
// ---------------------------------------------------------------------------
__global__ __launch_bounds__(256) void prep_kernel(
    const float* __restrict__ W1, const float* __restrict__ W2,
    ushort* __restrict__ W1s, ushort* __restrict__ W2s)
{
    int gid = blockIdx.x * 256 + threadIdx.x;
    if (gid < 16384){
        int j = gid & 7, l = (gid >> 3) & 63, ki = (gid >> 9) & 1, ct = gid >> 10;
        int k = ki * 32 + ((l >> 4) << 3) + j;
        int n = ct * 16 + (l & 15);
        W1s[gid] = f2bf(W1[k * 256 + n]);
    } else {
        int g = gid - 16384;
        int j = g & 7, l = (g >> 3) & 63, ki = (g >> 9) & 7, ct = g >> 12;
        int k = ki * 32 + ((l >> 4) << 3) + j;
        int n = ct * 16 + (l & 15);
        W2s[g] = f2bf(W2[k * 64 + n]);
    }
}

// ---------------------------------------------------------------------------
// Patch embedder: all-MFMA, one block (4 waves) per patch. Writes r[384].
// launch_bounds(256,3): VGPR cap 168 — live state ~130 VGPRs; (256,5) capped
// at 48 and spilled ~400 MB/dispatch to scratch (round-5 counters).
// ---------------------------------------------------------------------------
__global__ __launch_bounds__(256, 3) void patch_kernel(
    const float* __restrict__ feats, const int* __restrict__ esrc,
    const int* __restrict__ edst, const float* __restrict__ eew,
    const ushort* __restrict__ W1s, const float* __restrict__ g1,
    const float* __restrict__ b1, const ushort* __restrict__ W2s,
    const float* __restrict__ g2, const float* __restrict__ b2,
    float* __restrict__ rbuf)
{
    __shared__ __align__(16) char smem[29184];
    float* s_A  = (float*)smem;              // [64][68] f32 (dies after frag extract)
    char*  s_h1 = smem;                      // bf16 half-h1, 64 rows x 272B, swizzled
    char*  s_G1 = smem + 17408;              // bf16 G1, 64 rows x 144B, swizzled
    float* s_deg = (float*)(smem + 26624);   // 128
    float* s_rs  = (float*)(smem + 27136);   // 128
    float* s_r   = (float*)(smem + 27648);   // 384

    const int tid  = threadIdx.x;
    const int p    = blockIdx.x;
    const int lane = tid & 63;
    const int wv   = tid >> 6;
    const int lnlo = lane & 15;
    const int lghi = lane >> 4;

    // feat B-frags direct from global; rows >= 50 are exact zeros (A~ cols are 0 there)
    float fl[2][8];
    {
        const float* fbase = feats + (size_t)p * 3200 + wv * 16 + lnlo;
        #pragma unroll
        for (int ki = 0; ki < 2; ++ki)
            #pragma unroll
            for (int j = 0; j < 8; ++j){
                int s = ki * 32 + lghi * 8 + j;
                fl[ki][j] = (s < NP_N) ? fbase[s * 64] : 0.f;
            }
    }
    int es = 0, ed = 0; float ewt = 0.f;
    if (tid < EP_N){
        es  = esrc[p * EP_N + tid];
        ed  = edst[p * EP_N + tid];
        ewt = eew[p * EP_N + tid];
    }
    for (int i = tid; i < 1088; i += 256)
        *(float4*)&s_A[i * 4] = make_float4(0.f, 0.f, 0.f, 0.f);
    if (tid < 128) s_deg[tid] = 0.f;
    __syncthreads();
    if (tid < EP_N){
        atomicAdd(&s_deg[es], 1.f);
        atomicAdd(&s_deg[64 + ed], 1.f);
    }
    float r0s = 0.f;
    #pragma unroll
    for (int ki = 0; ki < 2; ++ki)
        #pragma unroll
        for (int j = 0; j < 8; ++j)
            r0s += fl[ki][j];
    r0s += __shfl_xor(r0s, 16); r0s += __shfl_xor(r0s, 32);
    __syncthreads();
    if (tid < 128) s_rs[tid] = rsqrtf(fmaxf(s_deg[tid], 1.f));
    if (lghi == 0) s_r[wv * 16 + lnlo] = r0s * 0.02f;
    short8 fbf[2];
    #pragma unroll
    for (int ki = 0; ki < 2; ++ki)
        #pragma unroll
        for (int j = 0; j < 8; ++j)
            fbf[ki][j] = (short)f2bf(fl[ki][j]);
    __syncthreads();
    if (tid < EP_N)
        atomicAdd(&s_A[ed * 68 + es], ewt * s_rs[es] * s_rs[64 + ed]);
    __syncthreads();
    short8 afr[4][2];
    #pragma unroll
    for (int rt = 0; rt < 4; ++rt)
        #pragma unroll
        for (int ki = 0; ki < 2; ++ki){
            int row = rt * 16 + lnlo, k0 = ki * 32 + lghi * 8;
            float4 f0 = *(const float4*)&s_A[row * 68 + k0];
            float4 f1 = *(const float4*)&s_A[row * 68 + k0 + 4];
            short8 sv;
            sv[0] = (short)f2bf(f0.x); sv[1] = (short)f2bf(f0.y);
            sv[2] = (short)f2bf(f0.z); sv[3] = (short)f2bf(f0.w);
            sv[4] = (short)f2bf(f1.x); sv[5] = (short)f2bf(f1.y);
            sv[6] = (short)f2bf(f1.z); sv[7] = (short)f2bf(f1.w);
            afr[rt][ki] = sv;
        }
    f32x4 cacc[4];
    #pragma unroll
    for (int rt = 0; rt < 4; ++rt) cacc[rt] = (f32x4){0.f,0.f,0.f,0.f};
    #pragma unroll
    for (int rt = 0; rt < 4; ++rt){
        cacc[rt] = __builtin_amdgcn_mfma_f32_16x16x32_bf16(afr[rt][0], fbf[0], cacc[rt], 0,0,0);
        cacc[rt] = __builtin_amdgcn_mfma_f32_16x16x32_bf16(afr[rt][1], fbf[1], cacc[rt], 0,0,0);
    }
    #pragma unroll
    for (int rt = 0; rt < 4; ++rt)
        #pragma unroll
        for (int e = 0; e < 4; ++e){
            int row = rt * 16 + lghi * 4 + e;
            int col = wv * 16 + lnlo;
            *(ushort*)(s_G1 + row * 144 + ((col * 2) ^ ((row & 8) << 2))) = f2bf(cacc[rt][e]);
        }
    __syncthreads();

    f32x4 zacc[4];
    #pragma unroll
    for (int rt = 0; rt < 4; ++rt) zacc[rt] = (f32x4){0.f,0.f,0.f,0.f};

    for (int h = 0; h < 2; ++h){
        short8 ga[4][2];
        #pragma unroll
        for (int rt = 0; rt < 4; ++rt)
            #pragma unroll
            for (int ki = 0; ki < 2; ++ki){
                int row = rt * 16 + lnlo, k0 = ki * 32 + lghi * 8;
                ga[rt][ki] = *(const short8*)(s_G1 + row * 144 + ((k0 * 2) ^ ((row & 8) << 2)));
            }
        #pragma unroll
        for (int ctl = 0; ctl < 2; ++ctl){
            int ctg = h * 8 + wv * 2 + ctl;
            short8 wb0 = *(const short8*)&W1s[((ctg * 2 + 0) * 64 + lane) * 8];
            short8 wb1 = *(const short8*)&W1s[((ctg * 2 + 1) * 64 + lane) * 8];
            f32x4 m[4];
            #pragma unroll
            for (int rt = 0; rt < 4; ++rt) m[rt] = (f32x4){0.f,0.f,0.f,0.f};
            #pragma unroll
            for (int rt = 0; rt < 4; ++rt){
                m[rt] = __builtin_amdgcn_mfma_f32_16x16x32_bf16(ga[rt][0], wb0, m[rt], 0,0,0);
                m[rt] = __builtin_amdgcn_mfma_f32_16x16x32_bf16(ga[rt][1], wb1, m[rt], 0,0,0);
            }
            float s1 = 0.f, s2 = 0.f;
            #pragma unroll
            for (int rt = 0; rt < 4; ++rt)
                #pragma unroll
                for (int e = 0; e < 4; ++e){ float x = m[rt][e]; s1 += x; s2 += x*x; }
            s1 += __shfl_xor(s1, 16); s1 += __shfl_xor(s1, 32);
            s2 += __shfl_xor(s2, 16); s2 += __shfl_xor(s2, 32);
            float mu = s1 * 0.02f;
            float var = s2 * 0.02f - mu * mu;
            float rinv = rsqrtf(var + EPSV);
            int jg = ctg * 16 + lnlo;
            float sc = g1[jg] * rinv;
            float sh = b1[jg] - mu * sc;
            float r1p = 0.f;
            int jl = (wv * 2 + ctl) * 16 + lnlo;
            #pragma unroll
            for (int rt = 0; rt < 4; ++rt)
                #pragma unroll
                for (int e = 0; e < 4; ++e){
                    int row = rt * 16 + lghi * 4 + e;
                    float y = m[rt][e] * sc + sh;
                    float hh = (y >= 0.f) ? y : 0.01f * y;
                    hh = (row < NP_N) ? hh : 0.f;
                    r1p += hh;
                    *(ushort*)(s_h1 + row * 272 + ((jl * 2) ^ ((row & 8) << 2))) = f2bf(hh);
                }
            r1p += __shfl_xor(r1p, 16); r1p += __shfl_xor(r1p, 32);
            if (lghi == 0) s_r[64 + jg] = r1p * 0.02f;
        }
        __syncthreads();
        #pragma unroll
        for (int kil = 0; kil < 4; ++kil){
            short8 wb2 = *(const short8*)&W2s[((wv * 8 + h * 4 + kil) * 64 + lane) * 8];
            #pragma unroll
            for (int rt = 0; rt < 4; ++rt){
                int row = rt * 16 + lnlo, kl = kil * 32 + lghi * 8;
                short8 a = *(const short8*)(s_h1 + row * 272 + ((kl * 2) ^ ((row & 8) << 2)));
                zacc[rt] = __builtin_amdgcn_mfma_f32_16x16x32_bf16(a, wb2, zacc[rt], 0,0,0);
            }
        }
        __syncthreads();
    }

    uint pk[4][2];
    #pragma unroll
    for (int rt = 0; rt < 4; ++rt){
        pk[rt][0] = pack2(zacc[rt][0], zacc[rt][1]);
        pk[rt][1] = pack2(zacc[rt][2], zacc[rt][3]);
    }
    bool hi = (lghi >= 2);
    int lane_lo = (((lghi * 2 + 0) & 3) << 4) + lnlo;
    int lane_hi = (((lghi * 2 + 1) & 3) << 4) + lnlo;
    short8 zb[2];
    #pragma unroll
    for (int ki = 0; ki < 2; ++ki){
        uint sA = hi ? pk[ki*2+1][0] : pk[ki*2][0];
        uint sB = hi ? pk[ki*2+1][1] : pk[ki*2][1];
        uint w0 = (uint)__shfl((int)sA, lane_lo, 64);
        uint w1 = (uint)__shfl((int)sB, lane_lo, 64);
        uint w2 = (uint)__shfl((int)sA, lane_hi, 64);
        uint w3 = (uint)__shfl((int)sB, lane_hi, 64);
        short8 z;
        z[0] = (short)(w0 & 0xffff); z[1] = (short)(w0 >> 16);
        z[2] = (short)(w1 & 0xffff); z[3] = (short)(w1 >> 16);
        z[4] = (short)(w2 & 0xffff); z[5] = (short)(w2 >> 16);
        z[6] = (short)(w3 & 0xffff); z[7] = (short)(w3 >> 16);
        zb[ki] = z;
    }
    f32x4 oacc[4];
    #pragma unroll
    for (int rt = 0; rt < 4; ++rt) oacc[rt] = (f32x4){0.f,0.f,0.f,0.f};
    #pragma unroll
    for (int rt = 0; rt < 4; ++rt){
        oacc[rt] = __builtin_amdgcn_mfma_f32_16x16x32_bf16(afr[rt][0], zb[0], oacc[rt], 0,0,0);
        oacc[rt] = __builtin_amdgcn_mfma_f32_16x16x32_bf16(afr[rt][1], zb[1], oacc[rt], 0,0,0);
    }
    {
        float s1 = 0.f, s2 = 0.f;
        #pragma unroll
        for (int rt = 0; rt < 4; ++rt)
            #pragma unroll
            for (int e = 0; e < 4; ++e){ float x = oacc[rt][e]; s1 += x; s2 += x*x; }
        s1 += __shfl_xor(s1, 16); s1 += __shfl_xor(s1, 32);
        s2 += __shfl_xor(s2, 16); s2 += __shfl_xor(s2, 32);
        float mu = s1 * 0.02f;
        float var = s2 * 0.02f - mu * mu;
        float rinv = rsqrtf(var + EPSV);
        int c2 = wv * 16 + lnlo;
        float sc = g2[c2] * rinv;
        float sh = b2[c2] - mu * sc;
        float r2p = 0.f;
        #pragma unroll
        for (int rt = 0; rt < 4; ++rt)
            #pragma unroll
            for (int e = 0; e < 4; ++e){
                int row = rt * 16 + lghi * 4 + e;
                float y = oacc[rt][e] * sc + sh;
                float hh = (y >= 0.f) ? y : 0.01f * y;
                r2p += (row < NP_N) ? hh : 0.f;
            }
        r2p += __shfl_xor(r2p, 16); r2p += __shfl_xor(r2p, 32);
        if (lghi == 0) s_r[320 + c2] = r2p * 0.02f;
    }
    __syncthreads();
    if (tid < 96)
        *(float4*)&rbuf[(size_t)p * 384 + tid * 4] = *(const float4*)&s_r[tid * 4];
}

// ---------------------------------------------------------------------------
// emb = InstanceNorm(R @ We) + lrelu
// ---------------------------------------------------------------------------
__global__ __launch_bounds__(256) void emb_kernel(
    const float* __restrict__ rbuf, const float* __restrict__ We,
    float* __restrict__ emb)
{
    __shared__ float s_R[16 * 388];
    int tid = threadIdx.x;
    int rb = blockIdx.x * 16;
    for (int i = tid; i < 1536; i += 256){
        int r = i / 96, q = i - r * 96;
        *(float4*)&s_R[r * 388 + q * 4] =
            *(const float4*)&rbuf[(size_t)(rb + r) * 384 + q * 4];
    }
    __syncthreads();
    int r = tid >> 4, c0 = (tid & 15) * 8;
    float acc[8];
    #pragma unroll
    for (int j = 0; j < 8; ++j) acc[j] = 0.f;
    for (int k = 0; k < 384; ++k){
        float a = s_R[r * 388 + k];
        const float* wp = &We[k * 128 + c0];
        #pragma unroll
        for (int j = 0; j < 8; ++j) acc[j] = fmaf(a, wp[j], acc[j]);
    }
    float s1 = 0.f, s2 = 0.f;
    #pragma unroll
    for (int j = 0; j < 8; ++j){ s1 += acc[j]; s2 += acc[j] * acc[j]; }
    s1 += __shfl_xor(s1, 1); s2 += __shfl_xor(s2, 1);
    s1 += __shfl_xor(s1, 2); s2 += __shfl_xor(s2, 2);
    s1 += __shfl_xor(s1, 4); s2 += __shfl_xor(s2, 4);
    s1 += __shfl_xor(s1, 8); s2 += __shfl_xor(s2, 8);
    float mu = s1 * (1.f / 128.f);
    float var = s2 * (1.f / 128.f) - mu * mu;
    float rinv = rsqrtf(var + EPSV);
    float o[8];
    #pragma unroll
    for (int j = 0; j < 8; ++j){
        float y = (acc[j] - mu) * rinv;
        o[j] = (y >= 0.f) ? y : 0.01f * y;
    }
    float* op = &emb[(size_t)(rb + r) * 128 + c0];
    *(float4*)op = make_float4(o[0], o[1], o[2], o[3]);
    *(float4*)(op + 4) = make_float4(o[4], o[5], o[6], o[7]);
}

// ---------------------------------------------------------------------------
// Mesh CSR build
// ---------------------------------------------------------------------------
__global__ __launch_bounds__(256) void deg_kernel(
    const int* __restrict__ msrc, const int* __restrict__ mdst,
    float* __restrict__ degO, float* __restrict__ degI)
{
    int e = blockIdx.x * 256 + threadIdx.x;
    if (e < EM_N){
        atomicAdd(&degO[msrc[e]], 1.f);
        atomicAdd(&degI[mdst[e]], 1.f);
    }
}

__global__ __launch_bounds__(256) void scan_kernel(
    const float* __restrict__ degI, int* __restrict__ offs)
{
    __shared__ int s_sc[256];
    int t = threadIdx.x;
    int sum = 0;
    for (int k = 0; k < 40; ++k){ int i = t * 40 + k; if (i < PM) sum += (int)degI[i]; }
    s_sc[t] = sum;
    __syncthreads();
    for (int off = 1; off < 256; off <<= 1){
        int v = (t >= off) ? s_sc[t - off] : 0;
        __syncthreads();
        s_sc[t] += v;
        __syncthreads();
    }
    int run = s_sc[t] - sum;
    for (int k = 0; k < 40; ++k){
        int i = t * 40 + k;
        if (i < PM){ offs[i] = run; run += (int)degI[i]; }
    }
    if (t == 255) offs[PM] = s_sc[255];
}

__global__ __launch_bounds__(256) void fill_kernel(
    const int* __restrict__ msrc, const int* __restrict__ mdst,
    const float* __restrict__ mew, const float* __restrict__ degO,
    const int* __restrict__ offs, int* __restrict__ cur,
    int* __restrict__ csrc, float* __restrict__ csw)
{
    int e = blockIdx.x * 256 + threadIdx.x;
    if (e < EM_N){
        int d = mdst[e], s = msrc[e];
        int pos = atomicAdd(&cur[d], 1);
        int idx = offs[d] + pos;
        csrc[idx] = s;
        csw[idx] = mew[e] * rsqrtf(fmaxf(degO[s], 1.f));
    }
}

// ---------------------------------------------------------------------------
// gather1: node-per-wave. agg1[d][128] = rsI(d) * sum_e csw * emb[src]
// ---------------------------------------------------------------------------
__global__ __launch_bounds__(256) void gather1_kernel(
    const float* __restrict__ emb, const int* __restrict__ offs,
    const int* __restrict__ csrc, const float* __restrict__ csw,
    const float* __restrict__ degI, float* __restrict__ agg1)
{
    int lane = threadIdx.x & 63, wv = threadIdx.x >> 6;
    int d = blockIdx.x * 4 + wv;
    int e0 = offs[d], e1 = offs[d + 1];
    float a0 = 0.f, a1 = 0.f;
    const float* ebase = emb + lane * 2;
    int e = e0;
    for (; e + 2 <= e1; e += 2){
        int s0 = csrc[e], s1 = csrc[e + 1];
        float w0 = csw[e], w1 = csw[e + 1];
        float2 v0 = *(const float2*)(ebase + (size_t)s0 * 128);
        float2 v1 = *(const float2*)(ebase + (size_t)s1 * 128);
        a0 = fmaf(v0.x, w0, a0); a1 = fmaf(v0.y, w0, a1);
        a0 = fmaf(v1.x, w1, a0); a1 = fmaf(v1.y, w1, a1);
    }
    if (e < e1){
        int s0 = csrc[e]; float w0 = csw[e];
        float2 v0 = *(const float2*)(ebase + (size_t)s0 * 128);
        a0 = fmaf(v0.x, w0, a0); a1 = fmaf(v0.y, w0, a1);
    }
    float rs = rsqrtf(fmaxf(degI[d], 1.f));
    *(float2*)&agg1[(size_t)d * 128 + lane * 2] = make_float2(a0 * rs, a1 * rs);
}

// ---------------------------------------------------------------------------
// gemm1: x1[row][c] = sum_k agg1[row][k] * Wc1[k][c], fused col stats.
// ---------------------------------------------------------------------------
__global__ __launch_bounds__(256) void gemm1_kernel(
    const float* __restrict__ agg1, const float* __restrict__ Wc1,
    float* __restrict__ x1, float* __restrict__ sums, float* __restrict__ sumsq)
{
    __shared__ float s_A[64 * 129];
    int tid = threadIdx.x, lane = tid & 63, w = tid >> 6;
    int rb = blockIdx.x * 64;
    for (int i = tid; i < 2048; i += 256){
        int r = i >> 5, q = i & 31;
        float4 v = (rb + r < PM)
            ? *(const float4*)&agg1[(size_t)(rb + r) * 128 + q * 4]
            : make_float4(0.f, 0.f, 0.f, 0.f);
        float* dst = &s_A[r * 129 + q * 4];
        dst[0] = v.x; dst[1] = v.y; dst[2] = v.z; dst[3] = v.w;
    }
    __syncthreads();
    int c0 = blockIdx.y * 64 + w * 16;
    float acc[16];
    #pragma unroll
    for (int jj = 0; jj < 16; ++jj) acc[jj] = 0.f;
    #pragma unroll 4
    for (int k = 0; k < 128; ++k){
        float a = s_A[lane * 129 + k];
        const float* wp = &Wc1[k * 256 + c0];
        #pragma unroll
        for (int jj = 0; jj < 16; ++jj) acc[jj] = fmaf(a, wp[jj], acc[jj]);
    }
    int row = rb + lane;
    if (row < PM){
        #pragma unroll
        for (int q = 0; q < 4; ++q)
            *(float4*)&x1[(size_t)row * 256 + c0 + q * 4] =
                make_float4(acc[q*4], acc[q*4+1], acc[q*4+2], acc[q*4+3]);
    }
    #pragma unroll
    for (int jj = 0; jj < 16; ++jj){
        float s1 = acc[jj], s2 = acc[jj] * acc[jj];
        #pragma unroll
        for (int m = 32; m; m >>= 1){ s1 += __shfl_xor(s1, m); s2 += __shfl_xor(s2, m); }
        if (lane == 0){
            atomicAdd(&sums[c0 + jj], s1);
            atomicAdd(&sumsq[c0 + jj], s2);
        }
    }
}

// ---------------------------------------------------------------------------
// norm1: row-major norm + lrelu -> hRow bf16, fused readout. grid 625
// ---------------------------------------------------------------------------
__global__ __launch_bounds__(256) void norm1_kernel(
    const float* __restrict__ x1, const float* __restrict__ sums,
    const float* __restrict__ sumsq, const float* __restrict__ g,
    const float* __restrict__ b, float* __restrict__ ro, ushort* __restrict__ hRow)
{
    int tid = threadIdx.x;
    int rb = blockIdx.x * 16;
    float mu = sums[tid] * (1.f / PM);
    float var = sumsq[tid] * (1.f / PM) - mu * mu;
    float sc = g[tid] * rsqrtf(var + EPSV);
    float sh = b[tid] - mu * sc;
    float lsum = 0.f;
    #pragma unroll 4
    for (int i = 0; i < 16; ++i){
        float x = x1[(size_t)(rb + i) * 256 + tid];
        float y = sc * x + sh;
        float h = (y >= 0.f) ? y : 0.01f * y;
        lsum += h;
        hRow[(size_t)(rb + i) * 256 + tid] = f2bf(h);
    }
    atomicAdd(&ro[tid], lsum);
}

// ---------------------------------------------------------------------------
// gather2: node-per-wave over hRow bf16. agg2 bf16 [PM][256]. grid 2500
// ---------------------------------------------------------------------------
__global__ __launch_bounds__(256) void gather2_kernel(
    const ushort* __restrict__ hRow, const int* __restrict__ offs,
    const int* __restrict__ csrc, const float* __restrict__ csw,
    const float* __restrict__ degI, uint* __restrict__ agg2)
{
    int lane = threadIdx.x & 63, wv = threadIdx.x >> 6;
    int d = blockIdx.x * 4 + wv;
    int e0 = offs[d], e1 = offs[d + 1];
    float a0 = 0.f, a1 = 0.f, a2 = 0.f, a3 = 0.f;
    const ushort* hbase = hRow + lane * 4;
    int e = e0;
    for (; e + 2 <= e1; e += 2){
        int s0 = csrc[e], s1 = csrc[e + 1];
        float w0 = csw[e], w1 = csw[e + 1];
        uint2 q0 = *(const uint2*)(hbase + (size_t)s0 * 256);
        uint2 q1 = *(const uint2*)(hbase + (size_t)s1 * 256);
        a0 = fmaf(__uint_as_float(q0.x << 16), w0, a0);
        a1 = fmaf(__uint_as_float(q0.x & 0xffff0000u), w0, a1);
        a2 = fmaf(__uint_as_float(q0.y << 16), w0, a2);
        a3 = fmaf(__uint_as_float(q0.y & 0xffff0000u), w0, a3);
        a0 = fmaf(__uint_as_float(q1.x << 16), w1, a0);
        a1 = fmaf(__uint_as_float(q1.x & 0xffff0000u), w1, a1);
        a2 = fmaf(__uint_as_float(q1.y << 16), w1, a2);
        a3 = fmaf(__uint_as_float(q1.y & 0xffff0000u), w1, a3);
    }
    if (e < e1){
        int s0 = csrc[e]; float w0 = csw[e];
        uint2 q0 = *(const uint2*)(hbase + (size_t)s0 * 256);
        a0 = fmaf(__uint_as_float(q0.x << 16), w0, a0);
        a1 = fmaf(__uint_as_float(q0.x & 0xffff0000u), w0, a1);
        a2 = fmaf(__uint_as_float(q0.y << 16), w0, a2);
        a3 = fmaf(__uint_as_float(q0.y & 0xffff0000u), w0, a3);
    }
    float rs = rsqrtf(fmaxf(degI[d], 1.f));
    uint2 o;
    o.x = pack2(a0 * rs, a1 * rs);
    o.y = pack2(a2 * rs, a3 * rs);
    *(uint2*)&agg2[(size_t)d * 128 + lane * 2] = o;
}

// ---------------------------------------------------------------------------
// gemm2: x2[row][c] = sum_k agg2[row][k] * Wc2[k][c] (K=256 bf16), fused stats
// ---------------------------------------------------------------------------
__global__ __launch_bounds__(256) void gemm2_kernel(
    const uint* __restrict__ agg2, const float* __restrict__ Wc2,
    float* __restrict__ x2, float* __restrict__ sums, float* __restrict__ sumsq)
{
    __shared__ uint s_A[64 * 129];
    int tid = threadIdx.x, lane = tid & 63, w = tid >> 6;
    int rb = blockIdx.x * 64;
    for (int i = tid; i < 4096; i += 256){
        int r = i >> 6, q = i & 63;
        uint2 v = (rb + r < PM)
            ? *(const uint2*)&agg2[(size_t)(rb + r) * 128 + q * 2]
            : make_uint2(0u, 0u);
        s_A[r * 129 + q * 2]     = v.x;
        s_A[r * 129 + q * 2 + 1] = v.y;
    }
    __syncthreads();
    int c0 = blockIdx.y * 64 + w * 16;
    float acc[16];
    #pragma unroll
    for (int jj = 0; jj < 16; ++jj) acc[jj] = 0.f;
    #pragma unroll 2
    for (int q = 0; q < 128; ++q){
        uint u = s_A[lane * 129 + q];
        float alo = __uint_as_float(u << 16);
        float ahi = __uint_as_float(u & 0xffff0000u);
        const float* wp0 = &Wc2[(2 * q) * 256 + c0];
        const float* wp1 = &Wc2[(2 * q + 1) * 256 + c0];
        #pragma unroll
        for (int jj = 0; jj < 16; ++jj){
            acc[jj] = fmaf(alo, wp0[jj], acc[jj]);
            acc[jj] = fmaf(ahi, wp1[jj], acc[jj]);
        }
    }
    int row = rb + lane;
    if (row < PM){
        #pragma unroll
        for (int q = 0; q < 4; ++q)
            *(float4*)&x2[(size_t)row * 256 + c0 + q * 4] =
                make_float4(acc[q*4], acc[q*4+1], acc[q*4+2], acc[q*4+3]);
    }
    #pragma unroll
    for (int jj = 0; jj < 16; ++jj){
        float s1 = acc[jj], s2 = acc[jj] * acc[jj];
        #pragma unroll
        for (int m = 32; m; m >>= 1){ s1 += __shfl_xor(s1, m); s2 += __shfl_xor(s2, m); }
        if (lane == 0){
            atomicAdd(&sums[c0 + jj], s1);
            atomicAdd(&sumsq[c0 + jj], s2);
        }
    }
}

// ---------------------------------------------------------------------------
// norm2: row-major norm + lrelu + readout (no store). grid 625
// ---------------------------------------------------------------------------
__global__ __launch_bounds__(256) void norm2_kernel(
    const float* __restrict__ x2, const float* __restrict__ sums,
    const float* __restrict__ sumsq, const float* __restrict__ g,
    const float* __restrict__ b, float* __restrict__ ro)
{
    int tid = threadIdx.x;
    int rb = blockIdx.x * 16;
    float mu = sums[tid] * (1.f / PM);
    float var = sumsq[tid] * (1.f / PM) - mu * mu;
    float sc = g[tid] * rsqrtf(var + EPSV);
    float sh = b[tid] - mu * sc;
    float lsum = 0.f;
    #pragma unroll 4
    for (int i = 0; i < 16; ++i){
        float x = x2[(size_t)(rb + i) * 256 + tid];
        float y = sc * x + sh;
        lsum += (y >= 0.f) ? y : 0.01f * y;
    }
    atomicAdd(&ro[tid], lsum);
}

__global__ __launch_bounds__(256) void final_kernel(
    const float* __restrict__ ro, const float* __restrict__ Wcls,
    float* __restrict__ out)
{
    __shared__ float s_part[256];
    int tid = threadIdx.x;
    int o = tid & 15, seg = tid >> 4;
    float pacc = 0.f;
    for (int j = seg * 32; j < seg * 32 + 32; ++j)
        pacc = fmaf(ro[j] * (1.f / PM), Wcls[j * OUT_C + o], pacc);
    s_part[tid] = pacc;
    __syncthreads();
    if (tid < OUT_C){
        float a = 0.f;
        #pragma unroll
        for (int s = 0; s < 16; ++s) a += s_part[s * 16 + tid];
        out[tid] = a;
    }
}

extern "C" void kernel_launch(void* const* d_in, const int* in_sizes, int n_in,
                              void* d_out, int out_size, void* d_ws, size_t ws_size,
                              hipStream_t stream) {
    const float* feats = (const float*)d_in[0];
    const int*   psrc  = (const int*)d_in[1];
    const int*   pdst  = (const int*)d_in[2];
    const float* pew   = (const float*)d_in[3];
    const int*   msrc  = (const int*)d_in[4];
    const int*   mdst  = (const int*)d_in[5];
    const float* mew   = (const float*)d_in[6];
    const float* W1    = (const float*)d_in[7];
    const float* g1    = (const float*)d_in[8];
    const float* b1    = (const float*)d_in[9];
    const float* W2    = (const float*)d_in[10];
    const float* g2    = (const float*)d_in[11];
    const float* b2    = (const float*)d_in[12];
    const float* We    = (const float*)d_in[13];
    const float* Wc1   = (const float*)d_in[14];
    const float* g3    = (const float*)d_in[15];
    const float* b3    = (const float*)d_in[16];
    const float* Wc2   = (const float*)d_in[17];
    const float* g4    = (const float*)d_in[18];
    const float* b4    = (const float*)d_in[19];
    const float* Wcls  = (const float*)d_in[20];
    float* out = (float*)d_out;
    float* ws  = (float*)d_ws;

    float*  degO  = ws + OFF_DEGO;
    float*  degI  = ws + OFF_DEGI;
    int*    offs  = (int*)(ws + OFF_OFFS);
    int*    cur   = (int*)(ws + OFF_CUR);
    int*    csrc  = (int*)(ws + OFF_CSRC);
    float*  csw   = ws + OFF_CSRW;
    float*  sums1 = ws + OFF_STATS;
    float*  sumsq1= ws + OFF_STATS + 256;
    float*  sums2 = ws + OFF_STATS + 512;
    float*  sumsq2= ws + OFF_STATS + 768;
    float*  ro    = ws + OFF_STATS + 1024;   // [512]
    ushort* W1s   = (ushort*)(ws + OFF_W1S);
    ushort* W2s   = (ushort*)(ws + OFF_W2S);
    float*  rbuf  = ws + OFF_RBUF;
    float*  agg1  = ws + OFF_AGG1;           // overlays rbuf (dead after emb)
    uint*   agg2  = (uint*)(ws + OFF_AGG2);  // overlays agg1 (dead after gemm1)
    float*  x1    = ws + OFF_X1;
    float*  x2    = ws + OFF_X2;             // overlays x1 (dead after norm1)
    float*  emb   = ws + OFF_EMB;
    ushort* hRow  = (ushort*)(ws + OFF_HROW); // overlays emb (dead after gather1)

    hipMemsetAsync(degO, 0, 20032 * sizeof(float), stream);   // degO + degI
    hipMemsetAsync(cur,  0, 10016 * sizeof(int), stream);
    hipMemsetAsync(sums1,0, 1536 * sizeof(float), stream);    // stats + ro

    prep_kernel<<<128, 256, 0, stream>>>(W1, W2, W1s, W2s);
    patch_kernel<<<PM, 256, 0, stream>>>(feats, psrc, pdst, pew,
                                         W1s, g1, b1, W2s, g2, b2, rbuf);
    emb_kernel<<<625, 256, 0, stream>>>(rbuf, We, emb);
    deg_kernel<<<EM_N/256, 256, 0, stream>>>(msrc, mdst, degO, degI);
    scan_kernel<<<1, 256, 0, stream>>>(degI, offs);
    fill_kernel<<<EM_N/256, 256, 0, stream>>>(msrc, mdst, mew, degO, offs, cur, csrc, csw);
    gather1_kernel<<<2500, 256, 0, stream>>>(emb, offs, csrc, csw, degI, agg1);
    gemm1_kernel<<<dim3(157, 4), 256, 0, stream>>>(agg1, Wc1, x1, sums1, sumsq1);
    norm1_kernel<<<625, 256, 0, stream>>>(x1, sums1, sumsq1, g3, b3, ro, hRow);
    gather2_kernel<<<2500, 256, 0, stream>>>(hRow, offs, csrc, csw, degI, agg2);
    gemm2_kernel<<<dim3(157, 4), 256, 0, stream>>>(agg2, Wc2, x2, sums2, sumsq2);
    norm2_kernel<<<625, 256, 0, stream>>>(x2, sums2, sumsq2, g4, b4, ro + 256);
    final_kernel<<<1, 256, 0, stream>>>(ro, Wcls, out);
}